// Round 1
// baseline (1974.519 us; speedup 1.0000x reference)
//
#include <hip/hip_runtime.h>
#include <hip/hip_bf16.h>

constexpr int N    = 100000;
constexpr int E    = 1600000;
constexpr int NSG2 = 20000;
constexpr int NSG  = 2000;
constexpr int NG   = 64;
constexpr int D    = 64;
constexpr int L    = 5;

__device__ __forceinline__ float sigm(float x) { return 1.0f / (1.0f + expf(-x)); }
__device__ __forceinline__ float elu(float x)  { return x > 0.0f ? x : (expf(x) - 1.0f); }

// ---- WihP[l] = conv_W[l] @ gru_Wih[l]  (64x64 @ 64x192) ----
__global__ __launch_bounds__(256) void prep_kernel(const float* __restrict__ convW,
                                                   const float* __restrict__ Wih,
                                                   float* __restrict__ WihP) {
    int idx = blockIdx.x * 256 + threadIdx.x;   // L*64*192 = 61440
    if (idx >= L * 64 * 192) return;
    int l = idx / (64 * 192);
    int rem = idx % (64 * 192);
    int i = rem / 192, j = rem % 192;
    const float* W  = convW + l * 64 * 64;
    const float* Wi = Wih  + l * 64 * 192;
    float acc = 0.0f;
    for (int t = 0; t < 64; ++t) acc = fmaf(W[i * 64 + t], Wi[t * 192 + j], acc);
    WihP[idx] = acc;
}

// ---- CSR build ----
__global__ void count_kernel(const int* __restrict__ dst, int* __restrict__ counts) {
    for (int e = blockIdx.x * blockDim.x + threadIdx.x; e < E; e += gridDim.x * blockDim.x)
        atomicAdd(&counts[dst[e]], 1);
}

__global__ __launch_bounds__(1024) void scan_kernel(const int* __restrict__ counts,
                                                    int* __restrict__ rowptr,
                                                    int* __restrict__ cursor) {
    __shared__ int part[1024];
    int t = threadIdx.x;
    const int CH = (N + 1023) / 1024;  // 98
    int beg = t * CH, end = min(beg + CH, N);
    int sum = 0;
    for (int i = beg; i < end; ++i) sum += counts[i];
    part[t] = sum;
    __syncthreads();
    for (int off = 1; off < 1024; off <<= 1) {
        int v = (t >= off) ? part[t - off] : 0;
        __syncthreads();
        part[t] += v;
        __syncthreads();
    }
    int run = part[t] - sum;  // exclusive prefix
    for (int i = beg; i < end; ++i) {
        rowptr[i] = run;
        cursor[i] = run;
        run += counts[i];
    }
    if (t == 1023) rowptr[N] = part[1023];
}

__global__ void scatter_kernel(const int* __restrict__ src, const int* __restrict__ dst,
                               int* __restrict__ cursor, int* __restrict__ col) {
    for (int e = blockIdx.x * blockDim.x + threadIdx.x; e < E; e += gridDim.x * blockDim.x) {
        int d = dst[e];
        int pos = atomicAdd(&cursor[d], 1);
        col[pos] = src[e];
    }
}

// ---- x0 = z_emb[0][z].sum(1) ----
__global__ __launch_bounds__(256) void embed_kernel(const int* __restrict__ z,
                                                    const float* __restrict__ zemb0,
                                                    float* __restrict__ x) {
    int idx = blockIdx.x * 256 + threadIdx.x;  // N*64
    if (idx >= N * D) return;
    int n = idx >> 6, c = idx & 63;
    x[idx] = zemb0[z[n * 2] * 64 + c] + zemb0[z[n * 2 + 1] * 64 + c];
}

// ---- s[v] = sum_{e: dst==v} x[src[e]]  (one wave per node) ----
__global__ __launch_bounds__(256) void aggregate_kernel(const float* __restrict__ x,
                                                        const int* __restrict__ rowptr,
                                                        const int* __restrict__ col,
                                                        float* __restrict__ s) {
    int node = blockIdx.x * 4 + (threadIdx.x >> 6);
    int lane = threadIdx.x & 63;
    if (node >= N) return;
    int beg = rowptr[node], end = rowptr[node + 1];
    float acc = 0.0f;
    for (int i = beg; i < end; ++i) {
        int u = col[i];
        acc += x[u * 64 + lane];
    }
    s[node * 64 + lane] = acc;
}

// ---- fused GRU: gi = s@WihP + bih, gh = x@Whh + bhh, gates -> x_out ----
// block = 256 threads = 64 channels x 4 node-groups; 32 nodes per block, 8 per thread
__global__ __launch_bounds__(256) void gru_kernel(const float* __restrict__ sbuf,
                                                  const float* __restrict__ xbuf,
                                                  const float* __restrict__ WihP_l,
                                                  const float* __restrict__ Whh_l,
                                                  const float* __restrict__ bih_l,
                                                  const float* __restrict__ bhh_l,
                                                  float* __restrict__ xout) {
    __shared__ float s_t[32][64];
    __shared__ float x_t[32][64];
    int tid = threadIdx.x;
    int c = tid & 63, g = tid >> 6;
    int node0 = blockIdx.x * 32;

    const float4* s4 = (const float4*)(sbuf + (size_t)node0 * 64);
    const float4* x4 = (const float4*)(xbuf + (size_t)node0 * 64);
    float4* st4 = (float4*)&s_t[0][0];
    float4* xt4 = (float4*)&x_t[0][0];
    st4[tid] = s4[tid]; st4[tid + 256] = s4[tid + 256];
    xt4[tid] = x4[tid]; xt4[tid + 256] = x4[tid + 256];
    __syncthreads();

    float a0[8] = {}, a1[8] = {}, a2[8] = {};
    float h0[8] = {}, h1[8] = {}, h2[8] = {};
    const int nb = g * 8;

    for (int k = 0; k < 64; ++k) {
        float wa0 = WihP_l[k * 192 + c];
        float wa1 = WihP_l[k * 192 + 64 + c];
        float wa2 = WihP_l[k * 192 + 128 + c];
        float wb0 = Whh_l[k * 192 + c];
        float wb1 = Whh_l[k * 192 + 64 + c];
        float wb2 = Whh_l[k * 192 + 128 + c];
#pragma unroll
        for (int n = 0; n < 8; ++n) {
            float sv = s_t[nb + n][k];
            float xv = x_t[nb + n][k];
            a0[n] = fmaf(sv, wa0, a0[n]);
            a1[n] = fmaf(sv, wa1, a1[n]);
            a2[n] = fmaf(sv, wa2, a2[n]);
            h0[n] = fmaf(xv, wb0, h0[n]);
            h1[n] = fmaf(xv, wb1, h1[n]);
            h2[n] = fmaf(xv, wb2, h2[n]);
        }
    }
    float bi0 = bih_l[c], bi1 = bih_l[64 + c], bi2 = bih_l[128 + c];
    float bh0 = bhh_l[c], bh1 = bhh_l[64 + c], bh2 = bhh_l[128 + c];
#pragma unroll
    for (int n = 0; n < 8; ++n) {
        float r  = sigm(a0[n] + bi0 + h0[n] + bh0);
        float zg = sigm(a1[n] + bi1 + h1[n] + bh1);
        float nn = tanhf(a2[n] + bi2 + r * (h2[n] + bh2));
        float xo = (1.0f - zg) * nn + zg * x_t[nb + n][c];
        xout[(size_t)(node0 + nb + n) * 64 + c] = xo;
    }
}

// ---- x = concat(x_prev, ze) @ trans_W + trans_b ----
__global__ __launch_bounds__(256) void transform_kernel(const float* __restrict__ xin,
                                                        const int* __restrict__ z,
                                                        const float* __restrict__ zemb_l,
                                                        const float* __restrict__ tW,
                                                        const float* __restrict__ tb,
                                                        float* __restrict__ xout) {
    __shared__ float xo_t[32][64];
    __shared__ float ze_t[32][64];
    int tid = threadIdx.x;
    int c = tid & 63, g = tid >> 6;
    int node0 = blockIdx.x * 32;

    const float4* x4 = (const float4*)(xin + (size_t)node0 * 64);
    float4* xt4 = (float4*)&xo_t[0][0];
    xt4[tid] = x4[tid]; xt4[tid + 256] = x4[tid + 256];
    for (int idx = tid; idx < 32 * 64; idx += 256) {
        int n = idx >> 6, k = idx & 63;
        int z0 = z[(node0 + n) * 2], z1 = z[(node0 + n) * 2 + 1];
        ze_t[n][k] = zemb_l[z0 * 64 + k] + zemb_l[z1 * 64 + k];
    }
    __syncthreads();

    float acc[8];
    float tbc = tb[c];
#pragma unroll
    for (int n = 0; n < 8; ++n) acc[n] = tbc;
    const int nb = g * 8;
    for (int k = 0; k < 128; ++k) {
        float w = tW[k * 64 + c];
        const float* srcp = (k < 64) ? &xo_t[0][0] : &ze_t[0][0];
        int kk = k & 63;
#pragma unroll
        for (int n = 0; n < 8; ++n)
            acc[n] = fmaf(srcp[(nb + n) * 64 + kk], w, acc[n]);
    }
#pragma unroll
    for (int n = 0; n < 8; ++n)
        xout[(size_t)(node0 + nb + n) * 64 + c] = acc[n];
}

// ---- segment-sum pooling via atomics ----
__global__ void pool_kernel(const float* __restrict__ in, const int* __restrict__ idx,
                            float* __restrict__ out, int rows) {
    int i = blockIdx.x * 256 + threadIdx.x;
    if (i >= rows * 64) return;
    int r = i >> 6, c = i & 63;
    atomicAdd(out + (size_t)idx[r] * 64 + c, in[i]);
}

// ---- in-place MLP: buf = relu(buf@W1+b1)@W2+b2, 4 rows per block ----
__global__ __launch_bounds__(256) void mlp_kernel(float* __restrict__ buf,
                                                  const float* __restrict__ W1,
                                                  const float* __restrict__ b1,
                                                  const float* __restrict__ W2,
                                                  const float* __restrict__ b2) {
    __shared__ float in_t[4][64];
    __shared__ float h_t[4][64];
    int tid = threadIdx.x;
    int c = tid & 63, r = tid >> 6;
    int row0 = blockIdx.x * 4;
    in_t[r][c] = buf[(size_t)(row0 + r) * 64 + c];
    __syncthreads();
    float acc = b1[c];
    for (int k = 0; k < 64; ++k) acc = fmaf(in_t[r][k], W1[k * 64 + c], acc);
    h_t[r][c] = fmaxf(acc, 0.0f);
    __syncthreads();
    acc = b2[c];
    for (int k = 0; k < 64; ++k) acc = fmaf(h_t[r][k], W2[k * 64 + c], acc);
    buf[(size_t)(row0 + r) * 64 + c] = acc;
}

// ---- final: g[64,64] -> fc1(elu) -> fc2(elu) -> fc3 -> out[64] ----
__global__ __launch_bounds__(256) void final_kernel(const float* __restrict__ g,
                                                    const float* __restrict__ fc1W, const float* __restrict__ fc1b,
                                                    const float* __restrict__ fc2W, const float* __restrict__ fc2b,
                                                    const float* __restrict__ fc3W, const float* __restrict__ fc3b,
                                                    float* __restrict__ out) {
    __shared__ float gt[64][64];
    __shared__ float h1[64][32];
    __shared__ float h2[64][16];
    int tid = threadIdx.x;
    for (int i = tid; i < 64 * 64; i += 256) gt[i >> 6][i & 63] = g[i];
    __syncthreads();
    for (int i = tid; i < 64 * 32; i += 256) {
        int r = i >> 5, c = i & 31;
        float acc = fc1b[c];
        for (int k = 0; k < 64; ++k) acc = fmaf(gt[r][k], fc1W[k * 32 + c], acc);
        h1[r][c] = elu(acc);
    }
    __syncthreads();
    for (int i = tid; i < 64 * 16; i += 256) {
        int r = i >> 4, c = i & 15;
        float acc = fc2b[c];
        for (int k = 0; k < 32; ++k) acc = fmaf(h1[r][k], fc2W[k * 16 + c], acc);
        h2[r][c] = elu(acc);
    }
    __syncthreads();
    if (tid < 64) {
        float acc = fc3b[0];
        for (int k = 0; k < 16; ++k) acc = fmaf(h2[tid][k], fc3W[k], acc);
        out[tid] = acc;
    }
}

extern "C" void kernel_launch(void* const* d_in, const int* in_sizes, int n_in,
                              void* d_out, int out_size, void* d_ws, size_t ws_size,
                              hipStream_t stream) {
    const int*   z     = (const int*)d_in[0];
    const int*   ei    = (const int*)d_in[1];
    const int*   n2s2  = (const int*)d_in[2];
    const int*   s22s  = (const int*)d_in[3];
    const int*   s2g   = (const int*)d_in[4];
    const float* z_emb = (const float*)d_in[5];
    const float* tW    = (const float*)d_in[6];
    const float* tb    = (const float*)d_in[7];
    const float* convW = (const float*)d_in[8];
    const float* gWih  = (const float*)d_in[9];
    const float* gbih  = (const float*)d_in[10];
    const float* gWhh  = (const float*)d_in[11];
    const float* gbhh  = (const float*)d_in[12];
    const float* epW1  = (const float*)d_in[13];
    const float* epb1  = (const float*)d_in[14];
    const float* epW2  = (const float*)d_in[15];
    const float* epb2  = (const float*)d_in[16];
    const float* npW1  = (const float*)d_in[17];
    const float* npb1  = (const float*)d_in[18];
    const float* npW2  = (const float*)d_in[19];
    const float* npb2  = (const float*)d_in[20];
    const float* fc1W  = (const float*)d_in[21];
    const float* fc1b  = (const float*)d_in[22];
    const float* fc2W  = (const float*)d_in[23];
    const float* fc2b  = (const float*)d_in[24];
    const float* fc3W  = (const float*)d_in[25];
    const float* fc3b  = (const float*)d_in[26];

    const int* srcp = ei;
    const int* dstp = ei + E;

    float* xbuf   = (float*)d_ws;            // N*64
    float* sbuf   = xbuf + (size_t)N * D;    // N*64
    float* WihP   = sbuf + (size_t)N * D;    // L*64*192
    int*   rowptr = (int*)(WihP + L * 64 * 192);  // N+1
    int*   cursor = rowptr + (N + 1);             // N
    int*   counts = cursor + N;                   // N
    int*   colbuf = counts + N;                   // E
    // pooling overlays on xbuf (free after last GRU)
    float* sg2  = xbuf;                 // NSG2*64
    float* sg   = sg2 + (size_t)NSG2 * D;  // NSG*64
    float* gbuf = sg + (size_t)NSG * D;    // 64*64

    hipMemsetAsync(counts, 0, (size_t)N * sizeof(int), stream);

    prep_kernel<<<(L * 64 * 192 + 255) / 256, 256, 0, stream>>>(convW, gWih, WihP);
    count_kernel<<<4096, 256, 0, stream>>>(dstp, counts);
    scan_kernel<<<1, 1024, 0, stream>>>(counts, rowptr, cursor);
    scatter_kernel<<<4096, 256, 0, stream>>>(srcp, dstp, cursor, colbuf);

    embed_kernel<<<(N * D + 255) / 256, 256, 0, stream>>>(z, z_emb, xbuf);

    for (int l = 0; l < L; ++l) {
        if (l > 0) {
            transform_kernel<<<N / 32, 256, 0, stream>>>(
                sbuf, z, z_emb + (size_t)l * 100 * 64,
                tW + (size_t)(l - 1) * 128 * 64, tb + (size_t)(l - 1) * 64, xbuf);
        }
        aggregate_kernel<<<(N + 3) / 4, 256, 0, stream>>>(xbuf, rowptr, colbuf, sbuf);
        gru_kernel<<<N / 32, 256, 0, stream>>>(
            sbuf, xbuf,
            WihP + (size_t)l * 64 * 192, gWhh + (size_t)l * 64 * 192,
            gbih + (size_t)l * 192, gbhh + (size_t)l * 192, sbuf);
    }

    // pooling chain: x_final lives in sbuf
    hipMemsetAsync(sg2, 0, (size_t)(NSG2 + NSG + NG) * D * sizeof(float), stream);
    pool_kernel<<<(N * D + 255) / 256, 256, 0, stream>>>(sbuf, n2s2, sg2, N);
    mlp_kernel<<<NSG2 / 4, 256, 0, stream>>>(sg2, epW1, epb1, epW2, epb2);
    pool_kernel<<<(NSG2 * D + 255) / 256, 256, 0, stream>>>(sg2, s22s, sg, NSG2);
    mlp_kernel<<<NSG / 4, 256, 0, stream>>>(sg, npW1, npb1, npW2, npb2);
    pool_kernel<<<(NSG * D + 255) / 256, 256, 0, stream>>>(sg, s2g, gbuf, NSG);
    final_kernel<<<1, 256, 0, stream>>>(gbuf, fc1W, fc1b, fc2W, fc2b, fc3W, fc3b, (float*)d_out);
}

// Round 2
// 1494.774 us; speedup vs baseline: 1.3209x; 1.3209x over previous
//
#include <hip/hip_runtime.h>
#include <hip/hip_bf16.h>

constexpr int N    = 100000;
constexpr int E    = 1600000;
constexpr int NSG2 = 20000;
constexpr int NSG  = 2000;
constexpr int NG   = 64;
constexpr int D    = 64;
constexpr int L    = 5;

constexpr int SCAN_BLK = 1024;
constexpr int SCAN_NB  = (N + SCAN_BLK - 1) / SCAN_BLK;  // 98

__device__ __forceinline__ float sigm(float x) { return 1.0f / (1.0f + expf(-x)); }
__device__ __forceinline__ float elu(float x)  { return x > 0.0f ? x : (expf(x) - 1.0f); }

// ---- WihP[l] = conv_W[l] @ gru_Wih[l]  (64x64 @ 64x192) ----
__global__ __launch_bounds__(256) void prep_kernel(const float* __restrict__ convW,
                                                   const float* __restrict__ Wih,
                                                   float* __restrict__ WihP) {
    int idx = blockIdx.x * 256 + threadIdx.x;   // L*64*192 = 61440
    if (idx >= L * 64 * 192) return;
    int l = idx / (64 * 192);
    int rem = idx % (64 * 192);
    int i = rem / 192, j = rem % 192;
    const float* W  = convW + l * 64 * 64;
    const float* Wi = Wih  + l * 64 * 192;
    float acc = 0.0f;
    for (int t = 0; t < 64; ++t) acc = fmaf(W[i * 64 + t], Wi[t * 192 + j], acc);
    WihP[idx] = acc;
}

// ---- CSR build ----
__global__ void count_kernel(const int* __restrict__ dst, int* __restrict__ counts) {
    for (int e = blockIdx.x * blockDim.x + threadIdx.x; e < E; e += gridDim.x * blockDim.x)
        atomicAdd(&counts[dst[e]], 1);
}

// 2-level coalesced scan: (1) per-block sums, (2) scan the 98 block sums,
// (3) per-block exclusive scan + offset -> rowptr & cursor
__global__ __launch_bounds__(1024) void scan1_kernel(const int* __restrict__ counts,
                                                     int* __restrict__ blocksum) {
    int i = blockIdx.x * SCAN_BLK + threadIdx.x;
    int v = (i < N) ? counts[i] : 0;
#pragma unroll
    for (int off = 32; off > 0; off >>= 1) v += __shfl_down(v, off, 64);
    __shared__ int ws[16];
    int wid = threadIdx.x >> 6, lane = threadIdx.x & 63;
    if (lane == 0) ws[wid] = v;
    __syncthreads();
    if (threadIdx.x == 0) {
        int s = 0;
#pragma unroll
        for (int w = 0; w < 16; ++w) s += ws[w];
        blocksum[blockIdx.x] = s;
    }
}

__global__ __launch_bounds__(128) void scan2_kernel(const int* __restrict__ blocksum,
                                                    int* __restrict__ blockoff) {
    __shared__ int sh[128];
    int t = threadIdx.x;
    int v = (t < SCAN_NB) ? blocksum[t] : 0;
    sh[t] = v;
    __syncthreads();
    for (int off = 1; off < 128; off <<= 1) {
        int u = (t >= off) ? sh[t - off] : 0;
        __syncthreads();
        sh[t] += u;
        __syncthreads();
    }
    if (t < SCAN_NB) blockoff[t] = sh[t] - v;  // exclusive
}

__global__ __launch_bounds__(1024) void scan3_kernel(const int* __restrict__ counts,
                                                     const int* __restrict__ blockoff,
                                                     int* __restrict__ rowptr,
                                                     int* __restrict__ cursor) {
    int i = blockIdx.x * SCAN_BLK + threadIdx.x;
    int v = (i < N) ? counts[i] : 0;
    int lane = threadIdx.x & 63, wid = threadIdx.x >> 6;
    int sv = v;
#pragma unroll
    for (int off = 1; off < 64; off <<= 1) {
        int u = __shfl_up(sv, off, 64);
        if (lane >= off) sv += u;
    }
    __shared__ int wsum[16];
    if (lane == 63) wsum[wid] = sv;
    __syncthreads();
    if (threadIdx.x == 0) {
        int r = 0;
#pragma unroll
        for (int w = 0; w < 16; ++w) { int t = wsum[w]; wsum[w] = r; r += t; }
    }
    __syncthreads();
    int excl = sv - v + wsum[wid] + blockoff[blockIdx.x];
    if (i < N) { rowptr[i] = excl; cursor[i] = excl; }
    if (i == N - 1) rowptr[N] = excl + v;
}

__global__ void scatter_kernel(const int* __restrict__ src, const int* __restrict__ dst,
                               int* __restrict__ cursor, int* __restrict__ col) {
    for (int e = blockIdx.x * blockDim.x + threadIdx.x; e < E; e += gridDim.x * blockDim.x) {
        int d = dst[e];
        int pos = atomicAdd(&cursor[d], 1);
        col[pos] = src[e];
    }
}

// ---- x0 = z_emb[0][z].sum(1) ----
__global__ __launch_bounds__(256) void embed_kernel(const int* __restrict__ z,
                                                    const float* __restrict__ zemb0,
                                                    float* __restrict__ x) {
    int idx = blockIdx.x * 256 + threadIdx.x;  // N*64
    if (idx >= N * D) return;
    int n = idx >> 6, c = idx & 63;
    x[idx] = zemb0[z[n * 2] * 64 + c] + zemb0[z[n * 2 + 1] * 64 + c];
}

// ---- s[v] = sum_{e: dst==v} x[src[e]]  (one wave per node, 2-way unrolled) ----
__global__ __launch_bounds__(256) void aggregate_kernel(const float* __restrict__ x,
                                                        const int* __restrict__ rowptr,
                                                        const int* __restrict__ col,
                                                        float* __restrict__ s) {
    int node = blockIdx.x * 4 + (threadIdx.x >> 6);
    int lane = threadIdx.x & 63;
    if (node >= N) return;
    int beg = rowptr[node], end = rowptr[node + 1];
    float acc0 = 0.0f, acc1 = 0.0f;
    int i = beg;
    for (; i + 2 <= end; i += 2) {
        int u0 = col[i], u1 = col[i + 1];
        acc0 += x[(size_t)u0 * 64 + lane];
        acc1 += x[(size_t)u1 * 64 + lane];
    }
    if (i < end) acc0 += x[(size_t)col[i] * 64 + lane];
    s[(size_t)node * 64 + lane] = acc0 + acc1;
}

// ---- fused GRU: gi = s@WihP + bih, gh = x@Whh + bhh, gates -> x_out ----
__global__ __launch_bounds__(256) void gru_kernel(const float* __restrict__ sbuf,
                                                  const float* __restrict__ xbuf,
                                                  const float* __restrict__ WihP_l,
                                                  const float* __restrict__ Whh_l,
                                                  const float* __restrict__ bih_l,
                                                  const float* __restrict__ bhh_l,
                                                  float* __restrict__ xout) {
    __shared__ float s_t[32][64];
    __shared__ float x_t[32][64];
    int tid = threadIdx.x;
    int c = tid & 63, g = tid >> 6;
    int node0 = blockIdx.x * 32;

    const float4* s4 = (const float4*)(sbuf + (size_t)node0 * 64);
    const float4* x4 = (const float4*)(xbuf + (size_t)node0 * 64);
    float4* st4 = (float4*)&s_t[0][0];
    float4* xt4 = (float4*)&x_t[0][0];
    st4[tid] = s4[tid]; st4[tid + 256] = s4[tid + 256];
    xt4[tid] = x4[tid]; xt4[tid + 256] = x4[tid + 256];
    __syncthreads();

    float a0[8] = {}, a1[8] = {}, a2[8] = {};
    float h0[8] = {}, h1[8] = {}, h2[8] = {};
    const int nb = g * 8;

    for (int k = 0; k < 64; ++k) {
        float wa0 = WihP_l[k * 192 + c];
        float wa1 = WihP_l[k * 192 + 64 + c];
        float wa2 = WihP_l[k * 192 + 128 + c];
        float wb0 = Whh_l[k * 192 + c];
        float wb1 = Whh_l[k * 192 + 64 + c];
        float wb2 = Whh_l[k * 192 + 128 + c];
#pragma unroll
        for (int n = 0; n < 8; ++n) {
            float sv = s_t[nb + n][k];
            float xv = x_t[nb + n][k];
            a0[n] = fmaf(sv, wa0, a0[n]);
            a1[n] = fmaf(sv, wa1, a1[n]);
            a2[n] = fmaf(sv, wa2, a2[n]);
            h0[n] = fmaf(xv, wb0, h0[n]);
            h1[n] = fmaf(xv, wb1, h1[n]);
            h2[n] = fmaf(xv, wb2, h2[n]);
        }
    }
    float bi0 = bih_l[c], bi1 = bih_l[64 + c], bi2 = bih_l[128 + c];
    float bh0 = bhh_l[c], bh1 = bhh_l[64 + c], bh2 = bhh_l[128 + c];
#pragma unroll
    for (int n = 0; n < 8; ++n) {
        float r  = sigm(a0[n] + bi0 + h0[n] + bh0);
        float zg = sigm(a1[n] + bi1 + h1[n] + bh1);
        float nn = tanhf(a2[n] + bi2 + r * (h2[n] + bh2));
        float xo = (1.0f - zg) * nn + zg * x_t[nb + n][c];
        xout[(size_t)(node0 + nb + n) * 64 + c] = xo;
    }
}

// ---- x = concat(x_prev, ze) @ trans_W + trans_b ----
__global__ __launch_bounds__(256) void transform_kernel(const float* __restrict__ xin,
                                                        const int* __restrict__ z,
                                                        const float* __restrict__ zemb_l,
                                                        const float* __restrict__ tW,
                                                        const float* __restrict__ tb,
                                                        float* __restrict__ xout) {
    __shared__ float xo_t[32][64];
    __shared__ float ze_t[32][64];
    int tid = threadIdx.x;
    int c = tid & 63, g = tid >> 6;
    int node0 = blockIdx.x * 32;

    const float4* x4 = (const float4*)(xin + (size_t)node0 * 64);
    float4* xt4 = (float4*)&xo_t[0][0];
    xt4[tid] = x4[tid]; xt4[tid + 256] = x4[tid + 256];
    for (int idx = tid; idx < 32 * 64; idx += 256) {
        int n = idx >> 6, k = idx & 63;
        int z0 = z[(node0 + n) * 2], z1 = z[(node0 + n) * 2 + 1];
        ze_t[n][k] = zemb_l[z0 * 64 + k] + zemb_l[z1 * 64 + k];
    }
    __syncthreads();

    float acc[8];
    float tbc = tb[c];
#pragma unroll
    for (int n = 0; n < 8; ++n) acc[n] = tbc;
    const int nb = g * 8;
    for (int k = 0; k < 128; ++k) {
        float w = tW[k * 64 + c];
        const float* srcp = (k < 64) ? &xo_t[0][0] : &ze_t[0][0];
        int kk = k & 63;
#pragma unroll
        for (int n = 0; n < 8; ++n)
            acc[n] = fmaf(srcp[(nb + n) * 64 + kk], w, acc[n]);
    }
#pragma unroll
    for (int n = 0; n < 8; ++n)
        xout[(size_t)(node0 + nb + n) * 64 + c] = acc[n];
}

// ---- segment-sum pooling via atomics ----
__global__ void pool_kernel(const float* __restrict__ in, const int* __restrict__ idx,
                            float* __restrict__ out, int rows) {
    int i = blockIdx.x * 256 + threadIdx.x;
    if (i >= rows * 64) return;
    int r = i >> 6, c = i & 63;
    atomicAdd(out + (size_t)idx[r] * 64 + c, in[i]);
}

// ---- in-place MLP: buf = relu(buf@W1+b1)@W2+b2, 4 rows per block ----
__global__ __launch_bounds__(256) void mlp_kernel(float* __restrict__ buf,
                                                  const float* __restrict__ W1,
                                                  const float* __restrict__ b1,
                                                  const float* __restrict__ W2,
                                                  const float* __restrict__ b2) {
    __shared__ float in_t[4][64];
    __shared__ float h_t[4][64];
    int tid = threadIdx.x;
    int c = tid & 63, r = tid >> 6;
    int row0 = blockIdx.x * 4;
    in_t[r][c] = buf[(size_t)(row0 + r) * 64 + c];
    __syncthreads();
    float acc = b1[c];
    for (int k = 0; k < 64; ++k) acc = fmaf(in_t[r][k], W1[k * 64 + c], acc);
    h_t[r][c] = fmaxf(acc, 0.0f);
    __syncthreads();
    acc = b2[c];
    for (int k = 0; k < 64; ++k) acc = fmaf(h_t[r][k], W2[k * 64 + c], acc);
    buf[(size_t)(row0 + r) * 64 + c] = acc;
}

// ---- final: g[64,64] -> fc1(elu) -> fc2(elu) -> fc3 -> out[64] ----
__global__ __launch_bounds__(256) void final_kernel(const float* __restrict__ g,
                                                    const float* __restrict__ fc1W, const float* __restrict__ fc1b,
                                                    const float* __restrict__ fc2W, const float* __restrict__ fc2b,
                                                    const float* __restrict__ fc3W, const float* __restrict__ fc3b,
                                                    float* __restrict__ out) {
    __shared__ float gt[64][64];
    __shared__ float h1[64][32];
    __shared__ float h2[64][16];
    int tid = threadIdx.x;
    for (int i = tid; i < 64 * 64; i += 256) gt[i >> 6][i & 63] = g[i];
    __syncthreads();
    for (int i = tid; i < 64 * 32; i += 256) {
        int r = i >> 5, c = i & 31;
        float acc = fc1b[c];
        for (int k = 0; k < 64; ++k) acc = fmaf(gt[r][k], fc1W[k * 32 + c], acc);
        h1[r][c] = elu(acc);
    }
    __syncthreads();
    for (int i = tid; i < 64 * 16; i += 256) {
        int r = i >> 4, c = i & 15;
        float acc = fc2b[c];
        for (int k = 0; k < 32; ++k) acc = fmaf(h1[r][k], fc2W[k * 16 + c], acc);
        h2[r][c] = elu(acc);
    }
    __syncthreads();
    if (tid < 64) {
        float acc = fc3b[0];
        for (int k = 0; k < 16; ++k) acc = fmaf(h2[tid][k], fc3W[k], acc);
        out[tid] = acc;
    }
}

extern "C" void kernel_launch(void* const* d_in, const int* in_sizes, int n_in,
                              void* d_out, int out_size, void* d_ws, size_t ws_size,
                              hipStream_t stream) {
    const int*   z     = (const int*)d_in[0];
    const int*   ei    = (const int*)d_in[1];
    const int*   n2s2  = (const int*)d_in[2];
    const int*   s22s  = (const int*)d_in[3];
    const int*   s2g   = (const int*)d_in[4];
    const float* z_emb = (const float*)d_in[5];
    const float* tW    = (const float*)d_in[6];
    const float* tb    = (const float*)d_in[7];
    const float* convW = (const float*)d_in[8];
    const float* gWih  = (const float*)d_in[9];
    const float* gbih  = (const float*)d_in[10];
    const float* gWhh  = (const float*)d_in[11];
    const float* gbhh  = (const float*)d_in[12];
    const float* epW1  = (const float*)d_in[13];
    const float* epb1  = (const float*)d_in[14];
    const float* epW2  = (const float*)d_in[15];
    const float* epb2  = (const float*)d_in[16];
    const float* npW1  = (const float*)d_in[17];
    const float* npb1  = (const float*)d_in[18];
    const float* npW2  = (const float*)d_in[19];
    const float* npb2  = (const float*)d_in[20];
    const float* fc1W  = (const float*)d_in[21];
    const float* fc1b  = (const float*)d_in[22];
    const float* fc2W  = (const float*)d_in[23];
    const float* fc2b  = (const float*)d_in[24];
    const float* fc3W  = (const float*)d_in[25];
    const float* fc3b  = (const float*)d_in[26];

    const int* srcp = ei;
    const int* dstp = ei + E;

    float* xbuf   = (float*)d_ws;            // N*64
    float* sbuf   = xbuf + (size_t)N * D;    // N*64
    float* WihP   = sbuf + (size_t)N * D;    // L*64*192
    int*   rowptr = (int*)(WihP + L * 64 * 192);  // N+1
    int*   cursor = rowptr + (N + 1);             // N
    int*   counts = cursor + N;                   // N
    int*   colbuf = counts + N;                   // E
    int*   blocksum = colbuf + E;                 // SCAN_NB
    int*   blockoff = blocksum + SCAN_NB;         // SCAN_NB
    // pooling overlays on xbuf (free after last GRU)
    float* sg2  = xbuf;                    // NSG2*64
    float* sg   = sg2 + (size_t)NSG2 * D;  // NSG*64
    float* gbuf = sg + (size_t)NSG * D;    // 64*64

    hipMemsetAsync(counts, 0, (size_t)N * sizeof(int), stream);

    prep_kernel<<<(L * 64 * 192 + 255) / 256, 256, 0, stream>>>(convW, gWih, WihP);
    count_kernel<<<4096, 256, 0, stream>>>(dstp, counts);
    scan1_kernel<<<SCAN_NB, SCAN_BLK, 0, stream>>>(counts, blocksum);
    scan2_kernel<<<1, 128, 0, stream>>>(blocksum, blockoff);
    scan3_kernel<<<SCAN_NB, SCAN_BLK, 0, stream>>>(counts, blockoff, rowptr, cursor);
    scatter_kernel<<<4096, 256, 0, stream>>>(srcp, dstp, cursor, colbuf);

    embed_kernel<<<(N * D + 255) / 256, 256, 0, stream>>>(z, z_emb, xbuf);

    for (int l = 0; l < L; ++l) {
        if (l > 0) {
            transform_kernel<<<N / 32, 256, 0, stream>>>(
                sbuf, z, z_emb + (size_t)l * 100 * 64,
                tW + (size_t)(l - 1) * 128 * 64, tb + (size_t)(l - 1) * 64, xbuf);
        }
        aggregate_kernel<<<(N + 3) / 4, 256, 0, stream>>>(xbuf, rowptr, colbuf, sbuf);
        gru_kernel<<<N / 32, 256, 0, stream>>>(
            sbuf, xbuf,
            WihP + (size_t)l * 64 * 192, gWhh + (size_t)l * 64 * 192,
            gbih + (size_t)l * 192, gbhh + (size_t)l * 192, sbuf);
    }

    // pooling chain: x_final lives in sbuf
    hipMemsetAsync(sg2, 0, (size_t)(NSG2 + NSG + NG) * D * sizeof(float), stream);
    pool_kernel<<<(N * D + 255) / 256, 256, 0, stream>>>(sbuf, n2s2, sg2, N);
    mlp_kernel<<<NSG2 / 4, 256, 0, stream>>>(sg2, epW1, epb1, epW2, epb2);
    pool_kernel<<<(NSG2 * D + 255) / 256, 256, 0, stream>>>(sg2, s22s, sg, NSG2);
    mlp_kernel<<<NSG / 4, 256, 0, stream>>>(sg, npW1, npb1, npW2, npb2);
    pool_kernel<<<(NSG * D + 255) / 256, 256, 0, stream>>>(sg, s2g, gbuf, NSG);
    final_kernel<<<1, 256, 0, stream>>>(gbuf, fc1W, fc1b, fc2W, fc2b, fc3W, fc3b, (float*)d_out);
}

// Round 3
// 1312.043 us; speedup vs baseline: 1.5049x; 1.1393x over previous
//
#include <hip/hip_runtime.h>
#include <hip/hip_bf16.h>

constexpr int N    = 100000;
constexpr int E    = 1600000;
constexpr int NSG2 = 20000;
constexpr int NSG  = 2000;
constexpr int NG   = 64;
constexpr int D    = 64;
constexpr int L    = 5;

constexpr int SCAN_BLK = 1024;
constexpr int SCAN_NB  = (N + SCAN_BLK - 1) / SCAN_BLK;  // 98

__device__ __forceinline__ float sigm(float x) { return 1.0f / (1.0f + expf(-x)); }
__device__ __forceinline__ float elu(float x)  { return x > 0.0f ? x : (expf(x) - 1.0f); }

// ---- WihP[l] = conv_W[l] @ gru_Wih[l]  (64x64 @ 64x192) ----
__global__ __launch_bounds__(256) void prep_kernel(const float* __restrict__ convW,
                                                   const float* __restrict__ Wih,
                                                   float* __restrict__ WihP) {
    int idx = blockIdx.x * 256 + threadIdx.x;   // L*64*192 = 61440
    if (idx >= L * 64 * 192) return;
    int l = idx / (64 * 192);
    int rem = idx % (64 * 192);
    int i = rem / 192, j = rem % 192;
    const float* W  = convW + l * 64 * 64;
    const float* Wi = Wih  + l * 64 * 192;
    float acc = 0.0f;
    for (int t = 0; t < 64; ++t) acc = fmaf(W[i * 64 + t], Wi[t * 192 + j], acc);
    WihP[idx] = acc;
}

// ---- CSR build ----
__global__ void count_kernel(const int* __restrict__ dst, int* __restrict__ counts) {
    for (int e = blockIdx.x * blockDim.x + threadIdx.x; e < E; e += gridDim.x * blockDim.x)
        atomicAdd(&counts[dst[e]], 1);
}

__global__ __launch_bounds__(1024) void scan1_kernel(const int* __restrict__ counts,
                                                     int* __restrict__ blocksum) {
    int i = blockIdx.x * SCAN_BLK + threadIdx.x;
    int v = (i < N) ? counts[i] : 0;
#pragma unroll
    for (int off = 32; off > 0; off >>= 1) v += __shfl_down(v, off, 64);
    __shared__ int ws[16];
    int wid = threadIdx.x >> 6, lane = threadIdx.x & 63;
    if (lane == 0) ws[wid] = v;
    __syncthreads();
    if (threadIdx.x == 0) {
        int s = 0;
#pragma unroll
        for (int w = 0; w < 16; ++w) s += ws[w];
        blocksum[blockIdx.x] = s;
    }
}

__global__ __launch_bounds__(128) void scan2_kernel(const int* __restrict__ blocksum,
                                                    int* __restrict__ blockoff) {
    __shared__ int sh[128];
    int t = threadIdx.x;
    int v = (t < SCAN_NB) ? blocksum[t] : 0;
    sh[t] = v;
    __syncthreads();
    for (int off = 1; off < 128; off <<= 1) {
        int u = (t >= off) ? sh[t - off] : 0;
        __syncthreads();
        sh[t] += u;
        __syncthreads();
    }
    if (t < SCAN_NB) blockoff[t] = sh[t] - v;  // exclusive
}

__global__ __launch_bounds__(1024) void scan3_kernel(const int* __restrict__ counts,
                                                     const int* __restrict__ blockoff,
                                                     int* __restrict__ rowptr,
                                                     int* __restrict__ cursor) {
    int i = blockIdx.x * SCAN_BLK + threadIdx.x;
    int v = (i < N) ? counts[i] : 0;
    int lane = threadIdx.x & 63, wid = threadIdx.x >> 6;
    int sv = v;
#pragma unroll
    for (int off = 1; off < 64; off <<= 1) {
        int u = __shfl_up(sv, off, 64);
        if (lane >= off) sv += u;
    }
    __shared__ int wsum[16];
    if (lane == 63) wsum[wid] = sv;
    __syncthreads();
    if (threadIdx.x == 0) {
        int r = 0;
#pragma unroll
        for (int w = 0; w < 16; ++w) { int t = wsum[w]; wsum[w] = r; r += t; }
    }
    __syncthreads();
    int excl = sv - v + wsum[wid] + blockoff[blockIdx.x];
    if (i < N) { rowptr[i] = excl; cursor[i] = excl; }
    if (i == N - 1) rowptr[N] = excl + v;
}

__global__ void scatter_kernel(const int* __restrict__ src, const int* __restrict__ dst,
                               int* __restrict__ cursor, int* __restrict__ col) {
    for (int e = blockIdx.x * blockDim.x + threadIdx.x; e < E; e += gridDim.x * blockDim.x) {
        int d = dst[e];
        int pos = atomicAdd(&cursor[d], 1);
        col[pos] = src[e];
    }
}

// ---- x0 = z_emb[0][z].sum(1) ----
__global__ __launch_bounds__(256) void embed_kernel(const int* __restrict__ z,
                                                    const float* __restrict__ zemb0,
                                                    float* __restrict__ x) {
    int idx = blockIdx.x * 256 + threadIdx.x;  // N*64
    if (idx >= N * D) return;
    int n = idx >> 6, c = idx & 63;
    x[idx] = zemb0[z[n * 2] * 64 + c] + zemb0[z[n * 2 + 1] * 64 + c];
}

// ---- s[v] = sum_{e: dst==v} x[src[e]] ----
// wave = 4 neighbor-slots x 16 lanes; each lane loads a float4 (16B).
// 2-way unrolled -> 8 rows (32 cache lines) in flight per wave.
__global__ __launch_bounds__(256) void aggregate_kernel(const float* __restrict__ x,
                                                        const int* __restrict__ rowptr,
                                                        const int* __restrict__ col,
                                                        float* __restrict__ s) {
    int node = blockIdx.x * 4 + (threadIdx.x >> 6);
    int lane = threadIdx.x & 63;
    if (node >= N) return;
    int grp = lane >> 4;   // neighbor slot 0..3
    int cl  = lane & 15;   // float4 index within row
    int beg = rowptr[node], end = rowptr[node + 1];

    float ax = 0.f, ay = 0.f, az = 0.f, aw = 0.f;
    int i = beg + grp;
    for (; i + 4 < end; i += 8) {
        int u0 = col[i];
        int u1 = col[i + 4];
        float4 v0 = ((const float4*)(x + (size_t)u0 * 64))[cl];
        float4 v1 = ((const float4*)(x + (size_t)u1 * 64))[cl];
        ax += v0.x + v1.x; ay += v0.y + v1.y;
        az += v0.z + v1.z; aw += v0.w + v1.w;
    }
    if (i < end) {
        int u = col[i];
        float4 v = ((const float4*)(x + (size_t)u * 64))[cl];
        ax += v.x; ay += v.y; az += v.z; aw += v.w;
    }
    // combine the 4 neighbor slots (lanes differing in bits 4,5)
#pragma unroll
    for (int off = 16; off < 64; off <<= 1) {
        ax += __shfl_xor(ax, off, 64);
        ay += __shfl_xor(ay, off, 64);
        az += __shfl_xor(az, off, 64);
        aw += __shfl_xor(aw, off, 64);
    }
    if (grp == 0) {
        float4 r; r.x = ax; r.y = ay; r.z = az; r.w = aw;
        ((float4*)(s + (size_t)node * 64))[cl] = r;
    }
}

// ---- fused GRU: gi = s@WihP + bih, gh = x@Whh + bhh, gates -> x_out ----
__global__ __launch_bounds__(256) void gru_kernel(const float* __restrict__ sbuf,
                                                  const float* __restrict__ xbuf,
                                                  const float* __restrict__ WihP_l,
                                                  const float* __restrict__ Whh_l,
                                                  const float* __restrict__ bih_l,
                                                  const float* __restrict__ bhh_l,
                                                  float* __restrict__ xout) {
    __shared__ float s_t[32][64];
    __shared__ float x_t[32][64];
    int tid = threadIdx.x;
    int c = tid & 63, g = tid >> 6;
    int node0 = blockIdx.x * 32;

    const float4* s4 = (const float4*)(sbuf + (size_t)node0 * 64);
    const float4* x4 = (const float4*)(xbuf + (size_t)node0 * 64);
    float4* st4 = (float4*)&s_t[0][0];
    float4* xt4 = (float4*)&x_t[0][0];
    st4[tid] = s4[tid]; st4[tid + 256] = s4[tid + 256];
    xt4[tid] = x4[tid]; xt4[tid + 256] = x4[tid + 256];
    __syncthreads();

    float a0[8] = {}, a1[8] = {}, a2[8] = {};
    float h0[8] = {}, h1[8] = {}, h2[8] = {};
    const int nb = g * 8;

    for (int k = 0; k < 64; ++k) {
        float wa0 = WihP_l[k * 192 + c];
        float wa1 = WihP_l[k * 192 + 64 + c];
        float wa2 = WihP_l[k * 192 + 128 + c];
        float wb0 = Whh_l[k * 192 + c];
        float wb1 = Whh_l[k * 192 + 64 + c];
        float wb2 = Whh_l[k * 192 + 128 + c];
#pragma unroll
        for (int n = 0; n < 8; ++n) {
            float sv = s_t[nb + n][k];
            float xv = x_t[nb + n][k];
            a0[n] = fmaf(sv, wa0, a0[n]);
            a1[n] = fmaf(sv, wa1, a1[n]);
            a2[n] = fmaf(sv, wa2, a2[n]);
            h0[n] = fmaf(xv, wb0, h0[n]);
            h1[n] = fmaf(xv, wb1, h1[n]);
            h2[n] = fmaf(xv, wb2, h2[n]);
        }
    }
    float bi0 = bih_l[c], bi1 = bih_l[64 + c], bi2 = bih_l[128 + c];
    float bh0 = bhh_l[c], bh1 = bhh_l[64 + c], bh2 = bhh_l[128 + c];
#pragma unroll
    for (int n = 0; n < 8; ++n) {
        float r  = sigm(a0[n] + bi0 + h0[n] + bh0);
        float zg = sigm(a1[n] + bi1 + h1[n] + bh1);
        float nn = tanhf(a2[n] + bi2 + r * (h2[n] + bh2));
        float xo = (1.0f - zg) * nn + zg * x_t[nb + n][c];
        xout[(size_t)(node0 + nb + n) * 64 + c] = xo;
    }
}

// ---- x = concat(x_prev, ze) @ trans_W + trans_b ----
__global__ __launch_bounds__(256) void transform_kernel(const float* __restrict__ xin,
                                                        const int* __restrict__ z,
                                                        const float* __restrict__ zemb_l,
                                                        const float* __restrict__ tW,
                                                        const float* __restrict__ tb,
                                                        float* __restrict__ xout) {
    __shared__ float xo_t[32][64];
    __shared__ float ze_t[32][64];
    int tid = threadIdx.x;
    int c = tid & 63, g = tid >> 6;
    int node0 = blockIdx.x * 32;

    const float4* x4 = (const float4*)(xin + (size_t)node0 * 64);
    float4* xt4 = (float4*)&xo_t[0][0];
    xt4[tid] = x4[tid]; xt4[tid + 256] = x4[tid + 256];
    for (int idx = tid; idx < 32 * 64; idx += 256) {
        int n = idx >> 6, k = idx & 63;
        int z0 = z[(node0 + n) * 2], z1 = z[(node0 + n) * 2 + 1];
        ze_t[n][k] = zemb_l[z0 * 64 + k] + zemb_l[z1 * 64 + k];
    }
    __syncthreads();

    float acc[8];
    float tbc = tb[c];
#pragma unroll
    for (int n = 0; n < 8; ++n) acc[n] = tbc;
    const int nb = g * 8;
    for (int k = 0; k < 128; ++k) {
        float w = tW[k * 64 + c];
        const float* srcp = (k < 64) ? &xo_t[0][0] : &ze_t[0][0];
        int kk = k & 63;
#pragma unroll
        for (int n = 0; n < 8; ++n)
            acc[n] = fmaf(srcp[(nb + n) * 64 + kk], w, acc[n]);
    }
#pragma unroll
    for (int n = 0; n < 8; ++n)
        xout[(size_t)(node0 + nb + n) * 64 + c] = acc[n];
}

// ---- segment-sum pooling via atomics ----
__global__ void pool_kernel(const float* __restrict__ in, const int* __restrict__ idx,
                            float* __restrict__ out, int rows) {
    int i = blockIdx.x * 256 + threadIdx.x;
    if (i >= rows * 64) return;
    int r = i >> 6, c = i & 63;
    atomicAdd(out + (size_t)idx[r] * 64 + c, in[i]);
}

// ---- in-place MLP: buf = relu(buf@W1+b1)@W2+b2, 4 rows per block ----
__global__ __launch_bounds__(256) void mlp_kernel(float* __restrict__ buf,
                                                  const float* __restrict__ W1,
                                                  const float* __restrict__ b1,
                                                  const float* __restrict__ W2,
                                                  const float* __restrict__ b2) {
    __shared__ float in_t[4][64];
    __shared__ float h_t[4][64];
    int tid = threadIdx.x;
    int c = tid & 63, r = tid >> 6;
    int row0 = blockIdx.x * 4;
    in_t[r][c] = buf[(size_t)(row0 + r) * 64 + c];
    __syncthreads();
    float acc = b1[c];
    for (int k = 0; k < 64; ++k) acc = fmaf(in_t[r][k], W1[k * 64 + c], acc);
    h_t[r][c] = fmaxf(acc, 0.0f);
    __syncthreads();
    acc = b2[c];
    for (int k = 0; k < 64; ++k) acc = fmaf(h_t[r][k], W2[k * 64 + c], acc);
    buf[(size_t)(row0 + r) * 64 + c] = acc;
}

// ---- final: g[64,64] -> fc1(elu) -> fc2(elu) -> fc3 -> out[64] ----
__global__ __launch_bounds__(256) void final_kernel(const float* __restrict__ g,
                                                    const float* __restrict__ fc1W, const float* __restrict__ fc1b,
                                                    const float* __restrict__ fc2W, const float* __restrict__ fc2b,
                                                    const float* __restrict__ fc3W, const float* __restrict__ fc3b,
                                                    float* __restrict__ out) {
    __shared__ float gt[64][64];
    __shared__ float h1[64][32];
    __shared__ float h2[64][16];
    int tid = threadIdx.x;
    for (int i = tid; i < 64 * 64; i += 256) gt[i >> 6][i & 63] = g[i];
    __syncthreads();
    for (int i = tid; i < 64 * 32; i += 256) {
        int r = i >> 5, c = i & 31;
        float acc = fc1b[c];
        for (int k = 0; k < 64; ++k) acc = fmaf(gt[r][k], fc1W[k * 32 + c], acc);
        h1[r][c] = elu(acc);
    }
    __syncthreads();
    for (int i = tid; i < 64 * 16; i += 256) {
        int r = i >> 4, c = i & 15;
        float acc = fc2b[c];
        for (int k = 0; k < 32; ++k) acc = fmaf(h1[r][k], fc2W[k * 16 + c], acc);
        h2[r][c] = elu(acc);
    }
    __syncthreads();
    if (tid < 64) {
        float acc = fc3b[0];
        for (int k = 0; k < 16; ++k) acc = fmaf(h2[tid][k], fc3W[k], acc);
        out[tid] = acc;
    }
}

extern "C" void kernel_launch(void* const* d_in, const int* in_sizes, int n_in,
                              void* d_out, int out_size, void* d_ws, size_t ws_size,
                              hipStream_t stream) {
    const int*   z     = (const int*)d_in[0];
    const int*   ei    = (const int*)d_in[1];
    const int*   n2s2  = (const int*)d_in[2];
    const int*   s22s  = (const int*)d_in[3];
    const int*   s2g   = (const int*)d_in[4];
    const float* z_emb = (const float*)d_in[5];
    const float* tW    = (const float*)d_in[6];
    const float* tb    = (const float*)d_in[7];
    const float* convW = (const float*)d_in[8];
    const float* gWih  = (const float*)d_in[9];
    const float* gbih  = (const float*)d_in[10];
    const float* gWhh  = (const float*)d_in[11];
    const float* gbhh  = (const float*)d_in[12];
    const float* epW1  = (const float*)d_in[13];
    const float* epb1  = (const float*)d_in[14];
    const float* epW2  = (const float*)d_in[15];
    const float* epb2  = (const float*)d_in[16];
    const float* npW1  = (const float*)d_in[17];
    const float* npb1  = (const float*)d_in[18];
    const float* npW2  = (const float*)d_in[19];
    const float* npb2  = (const float*)d_in[20];
    const float* fc1W  = (const float*)d_in[21];
    const float* fc1b  = (const float*)d_in[22];
    const float* fc2W  = (const float*)d_in[23];
    const float* fc2b  = (const float*)d_in[24];
    const float* fc3W  = (const float*)d_in[25];
    const float* fc3b  = (const float*)d_in[26];

    const int* srcp = ei;
    const int* dstp = ei + E;

    float* xbuf   = (float*)d_ws;            // N*64
    float* sbuf   = xbuf + (size_t)N * D;    // N*64
    float* WihP   = sbuf + (size_t)N * D;    // L*64*192
    int*   rowptr = (int*)(WihP + L * 64 * 192);  // N+1
    int*   cursor = rowptr + (N + 1);             // N
    int*   counts = cursor + N;                   // N
    int*   colbuf = counts + N;                   // E
    int*   blocksum = colbuf + E;                 // SCAN_NB
    int*   blockoff = blocksum + SCAN_NB;         // SCAN_NB
    // pooling overlays on xbuf (free after last GRU)
    float* sg2  = xbuf;                    // NSG2*64
    float* sg   = sg2 + (size_t)NSG2 * D;  // NSG*64
    float* gbuf = sg + (size_t)NSG * D;    // 64*64

    hipMemsetAsync(counts, 0, (size_t)N * sizeof(int), stream);

    prep_kernel<<<(L * 64 * 192 + 255) / 256, 256, 0, stream>>>(convW, gWih, WihP);
    count_kernel<<<4096, 256, 0, stream>>>(dstp, counts);
    scan1_kernel<<<SCAN_NB, SCAN_BLK, 0, stream>>>(counts, blocksum);
    scan2_kernel<<<1, 128, 0, stream>>>(blocksum, blockoff);
    scan3_kernel<<<SCAN_NB, SCAN_BLK, 0, stream>>>(counts, blockoff, rowptr, cursor);
    scatter_kernel<<<4096, 256, 0, stream>>>(srcp, dstp, cursor, colbuf);

    embed_kernel<<<(N * D + 255) / 256, 256, 0, stream>>>(z, z_emb, xbuf);

    for (int l = 0; l < L; ++l) {
        if (l > 0) {
            transform_kernel<<<N / 32, 256, 0, stream>>>(
                sbuf, z, z_emb + (size_t)l * 100 * 64,
                tW + (size_t)(l - 1) * 128 * 64, tb + (size_t)(l - 1) * 64, xbuf);
        }
        aggregate_kernel<<<(N + 3) / 4, 256, 0, stream>>>(xbuf, rowptr, colbuf, sbuf);
        gru_kernel<<<N / 32, 256, 0, stream>>>(
            sbuf, xbuf,
            WihP + (size_t)l * 64 * 192, gWhh + (size_t)l * 64 * 192,
            gbih + (size_t)l * 192, gbhh + (size_t)l * 192, sbuf);
    }

    // pooling chain: x_final lives in sbuf
    hipMemsetAsync(sg2, 0, (size_t)(NSG2 + NSG + NG) * D * sizeof(float), stream);
    pool_kernel<<<(N * D + 255) / 256, 256, 0, stream>>>(sbuf, n2s2, sg2, N);
    mlp_kernel<<<NSG2 / 4, 256, 0, stream>>>(sg2, epW1, epb1, epW2, epb2);
    pool_kernel<<<(NSG2 * D + 255) / 256, 256, 0, stream>>>(sg2, s22s, sg, NSG2);
    mlp_kernel<<<NSG / 4, 256, 0, stream>>>(sg, npW1, npb1, npW2, npb2);
    pool_kernel<<<(NSG * D + 255) / 256, 256, 0, stream>>>(sg, s2g, gbuf, NSG);
    final_kernel<<<1, 256, 0, stream>>>(gbuf, fc1W, fc1b, fc2W, fc2b, fc3W, fc3b, (float*)d_out);
}

// Round 4
// 732.074 us; speedup vs baseline: 2.6972x; 1.7922x over previous
//
#include <hip/hip_runtime.h>
#include <hip/hip_bf16.h>

constexpr int N    = 100000;
constexpr int E    = 1600000;
constexpr int NSG2 = 20000;
constexpr int NSG  = 2000;
constexpr int NG   = 64;
constexpr int D    = 64;
constexpr int L    = 5;

constexpr int SCAN_BLK = 1024;
constexpr int SCAN_NB  = (N + SCAN_BLK - 1) / SCAN_BLK;  // 98

typedef __attribute__((ext_vector_type(8))) short short8v;
typedef __attribute__((ext_vector_type(4))) float f32x4;

__device__ __forceinline__ float sigm(float x) { return 1.0f / (1.0f + expf(-x)); }
__device__ __forceinline__ float elu(float x)  { return x > 0.0f ? x : (expf(x) - 1.0f); }

__device__ __forceinline__ unsigned short f2b(float f) {
    union { float f; unsigned u; } x; x.f = f;
    unsigned r = (x.u + 0x7FFFu + ((x.u >> 16) & 1u)) >> 16;   // RNE
    return (unsigned short)r;
}

// ---- WihP[l] = conv_W[l] @ gru_Wih[l]  (64x64 @ 64x192) ----
__global__ __launch_bounds__(256) void prep_kernel(const float* __restrict__ convW,
                                                   const float* __restrict__ Wih,
                                                   float* __restrict__ WihP) {
    int idx = blockIdx.x * 256 + threadIdx.x;   // L*64*192 = 61440
    if (idx >= L * 64 * 192) return;
    int l = idx / (64 * 192);
    int rem = idx % (64 * 192);
    int i = rem / 192, j = rem % 192;
    const float* W  = convW + l * 64 * 64;
    const float* Wi = Wih  + l * 64 * 192;
    float acc = 0.0f;
    for (int t = 0; t < 64; ++t) acc = fmaf(W[i * 64 + t], Wi[t * 192 + j], acc);
    WihP[idx] = acc;
}

// ---- pack GRU weights into bf16 MFMA B-fragments ----
// Wgpk[(((l*2+mat)*12+nt)*2+t)*64+lane][8]; mat0=WihP, mat1=Whh
__global__ __launch_bounds__(256) void packg_kernel(const float* __restrict__ WihP,
                                                    const float* __restrict__ gWhh,
                                                    unsigned short* __restrict__ Wgpk) {
    int idx = blockIdx.x * 256 + threadIdx.x;
    if (idx >= L * 2 * 12 * 2 * 64) return;
    int lane = idx & 63;
    int r1 = idx >> 6;
    int t  = r1 & 1;
    int r2 = r1 >> 1;
    int nt = r2 % 12;
    int lm = r2 / 12;             // l*2+mat
    int mat = lm & 1, l = lm >> 1;
    const float* W = mat ? (gWhh + (size_t)l * 64 * 192) : (WihP + (size_t)l * 64 * 192);
    int n  = nt * 16 + (lane & 15);
    int k0 = t * 32 + (lane >> 4) * 8;
    short8v v;
#pragma unroll
    for (int j = 0; j < 8; ++j) v[j] = (short)f2b(W[(k0 + j) * 192 + n]);
    *(short8v*)(Wgpk + (size_t)idx * 8) = v;
}

// ---- pack transform weights: tWpk[((lm*4+nt)*4+t)*64+lane][8] ----
__global__ __launch_bounds__(256) void packt_kernel(const float* __restrict__ tW,
                                                    unsigned short* __restrict__ tWpk) {
    int idx = blockIdx.x * 256 + threadIdx.x;
    if (idx >= (L - 1) * 4 * 4 * 64) return;
    int lane = idx & 63;
    int r1 = idx >> 6;
    int t  = r1 & 3;
    int r2 = r1 >> 2;
    int nt = r2 & 3;
    int lm = r2 >> 2;
    const float* W = tW + (size_t)lm * 128 * 64;
    int n  = nt * 16 + (lane & 15);
    int k0 = t * 32 + (lane >> 4) * 8;
    short8v v;
#pragma unroll
    for (int j = 0; j < 8; ++j) v[j] = (short)f2b(W[(k0 + j) * 64 + n]);
    *(short8v*)(tWpk + (size_t)idx * 8) = v;
}

// ---- CSR build ----
__global__ void count_kernel(const int* __restrict__ dst, int* __restrict__ counts) {
    for (int e = blockIdx.x * blockDim.x + threadIdx.x; e < E; e += gridDim.x * blockDim.x)
        atomicAdd(&counts[dst[e]], 1);
}

__global__ __launch_bounds__(1024) void scan1_kernel(const int* __restrict__ counts,
                                                     int* __restrict__ blocksum) {
    int i = blockIdx.x * SCAN_BLK + threadIdx.x;
    int v = (i < N) ? counts[i] : 0;
#pragma unroll
    for (int off = 32; off > 0; off >>= 1) v += __shfl_down(v, off, 64);
    __shared__ int ws[16];
    int wid = threadIdx.x >> 6, lane = threadIdx.x & 63;
    if (lane == 0) ws[wid] = v;
    __syncthreads();
    if (threadIdx.x == 0) {
        int s = 0;
#pragma unroll
        for (int w = 0; w < 16; ++w) s += ws[w];
        blocksum[blockIdx.x] = s;
    }
}

__global__ __launch_bounds__(128) void scan2_kernel(const int* __restrict__ blocksum,
                                                    int* __restrict__ blockoff) {
    __shared__ int sh[128];
    int t = threadIdx.x;
    int v = (t < SCAN_NB) ? blocksum[t] : 0;
    sh[t] = v;
    __syncthreads();
    for (int off = 1; off < 128; off <<= 1) {
        int u = (t >= off) ? sh[t - off] : 0;
        __syncthreads();
        sh[t] += u;
        __syncthreads();
    }
    if (t < SCAN_NB) blockoff[t] = sh[t] - v;  // exclusive
}

__global__ __launch_bounds__(1024) void scan3_kernel(const int* __restrict__ counts,
                                                     const int* __restrict__ blockoff,
                                                     int* __restrict__ rowptr,
                                                     int* __restrict__ cursor) {
    int i = blockIdx.x * SCAN_BLK + threadIdx.x;
    int v = (i < N) ? counts[i] : 0;
    int lane = threadIdx.x & 63, wid = threadIdx.x >> 6;
    int sv = v;
#pragma unroll
    for (int off = 1; off < 64; off <<= 1) {
        int u = __shfl_up(sv, off, 64);
        if (lane >= off) sv += u;
    }
    __shared__ int wsum[16];
    if (lane == 63) wsum[wid] = sv;
    __syncthreads();
    if (threadIdx.x == 0) {
        int r = 0;
#pragma unroll
        for (int w = 0; w < 16; ++w) { int t = wsum[w]; wsum[w] = r; r += t; }
    }
    __syncthreads();
    int excl = sv - v + wsum[wid] + blockoff[blockIdx.x];
    if (i < N) { rowptr[i] = excl; cursor[i] = excl; }
    if (i == N - 1) rowptr[N] = excl + v;
}

__global__ void scatter_kernel(const int* __restrict__ src, const int* __restrict__ dst,
                               int* __restrict__ cursor, int* __restrict__ col) {
    for (int e = blockIdx.x * blockDim.x + threadIdx.x; e < E; e += gridDim.x * blockDim.x) {
        int d = dst[e];
        int pos = atomicAdd(&cursor[d], 1);
        col[pos] = src[e];
    }
}

// ---- x0 = z_emb[0][z].sum(1) ----
__global__ __launch_bounds__(256) void embed_kernel(const int* __restrict__ z,
                                                    const float* __restrict__ zemb0,
                                                    float* __restrict__ x) {
    int idx = blockIdx.x * 256 + threadIdx.x;  // N*64
    if (idx >= N * D) return;
    int n = idx >> 6, c = idx & 63;
    x[idx] = zemb0[z[n * 2] * 64 + c] + zemb0[z[n * 2 + 1] * 64 + c];
}

// ---- s[v] = sum_{e: dst==v} x[src[e]] : wave = 4 slots x 16 lanes, float4/lane ----
__global__ __launch_bounds__(256) void aggregate_kernel(const float* __restrict__ x,
                                                        const int* __restrict__ rowptr,
                                                        const int* __restrict__ col,
                                                        float* __restrict__ s) {
    int node = blockIdx.x * 4 + (threadIdx.x >> 6);
    int lane = threadIdx.x & 63;
    if (node >= N) return;
    int grp = lane >> 4;
    int cl  = lane & 15;
    int beg = rowptr[node], end = rowptr[node + 1];

    float ax = 0.f, ay = 0.f, az = 0.f, aw = 0.f;
    int i = beg + grp;
    for (; i + 4 < end; i += 8) {
        int u0 = col[i];
        int u1 = col[i + 4];
        float4 v0 = ((const float4*)(x + (size_t)u0 * 64))[cl];
        float4 v1 = ((const float4*)(x + (size_t)u1 * 64))[cl];
        ax += v0.x + v1.x; ay += v0.y + v1.y;
        az += v0.z + v1.z; aw += v0.w + v1.w;
    }
    if (i < end) {
        int u = col[i];
        float4 v = ((const float4*)(x + (size_t)u * 64))[cl];
        ax += v.x; ay += v.y; az += v.z; aw += v.w;
    }
#pragma unroll
    for (int off = 16; off < 64; off <<= 1) {
        ax += __shfl_xor(ax, off, 64);
        ay += __shfl_xor(ay, off, 64);
        az += __shfl_xor(az, off, 64);
        aw += __shfl_xor(aw, off, 64);
    }
    if (grp == 0) {
        float4 r; r.x = ax; r.y = ay; r.z = az; r.w = aw;
        ((float4*)(s + (size_t)node * 64))[cl] = r;
    }
}

// ---- MFMA GRU: 32 nodes/block, 4 waves; wave w owns channels [16w,16w+16) ----
__global__ __launch_bounds__(256) void gru_mfma_kernel(const float* __restrict__ sbuf,
                                                       const float* __restrict__ xbuf,
                                                       const unsigned short* __restrict__ Wgpk_l,
                                                       const float* __restrict__ bih,
                                                       const float* __restrict__ bhh,
                                                       float* __restrict__ xout) {
    __shared__ unsigned short s_lds[32][72];   // +8 pad: row stride 144B = 4-bank offset
    __shared__ unsigned short x_lds[32][72];
    int tid = threadIdx.x;
    int node0 = blockIdx.x * 32;

    const float4* s4 = (const float4*)(sbuf + (size_t)node0 * 64);
    const float4* x4 = (const float4*)(xbuf + (size_t)node0 * 64);
#pragma unroll
    for (int it = 0; it < 2; ++it) {
        int idx = it * 256 + tid;
        int r = idx >> 4, c4 = idx & 15;
        float4 v = s4[idx];
        ushort4 b; b.x = f2b(v.x); b.y = f2b(v.y); b.z = f2b(v.z); b.w = f2b(v.w);
        *(ushort4*)&s_lds[r][c4 * 4] = b;
        float4 u = x4[idx];
        ushort4 b2; b2.x = f2b(u.x); b2.y = f2b(u.y); b2.z = f2b(u.z); b2.w = f2b(u.w);
        *(ushort4*)&x_lds[r][c4 * 4] = b2;
    }
    __syncthreads();

    int lane = tid & 63, w = tid >> 6;
    int lr = lane & 15, lg = lane >> 4;

    short8v as_[2][2], ax_[2][2];
#pragma unroll
    for (int mt = 0; mt < 2; ++mt)
#pragma unroll
        for (int t = 0; t < 2; ++t) {
            int row = mt * 16 + lr, koff = t * 32 + lg * 8;
            as_[mt][t] = *(const short8v*)&s_lds[row][koff];
            ax_[mt][t] = *(const short8v*)&x_lds[row][koff];
        }

    f32x4 accA[3][2] = {};  // gi [gate][mt]
    f32x4 accB[3][2] = {};  // gh
#pragma unroll
    for (int g = 0; g < 3; ++g) {
        int nt = g * 4 + w;
#pragma unroll
        for (int t = 0; t < 2; ++t) {
            const unsigned short* pA = Wgpk_l + ((size_t)((0 * 12 + nt) * 2 + t) * 64 + lane) * 8;
            const unsigned short* pB = Wgpk_l + ((size_t)((1 * 12 + nt) * 2 + t) * 64 + lane) * 8;
            short8v bA = *(const short8v*)pA;
            short8v bB = *(const short8v*)pB;
#pragma unroll
            for (int mt = 0; mt < 2; ++mt) {
                accA[g][mt] = __builtin_amdgcn_mfma_f32_16x16x32_bf16(as_[mt][t], bA, accA[g][mt], 0, 0, 0);
                accB[g][mt] = __builtin_amdgcn_mfma_f32_16x16x32_bf16(ax_[mt][t], bB, accB[g][mt], 0, 0, 0);
            }
        }
    }

    int ch = w * 16 + lr;
    float bi0 = bih[ch], bi1 = bih[64 + ch], bi2 = bih[128 + ch];
    float bh0 = bhh[ch], bh1 = bhh[64 + ch], bh2 = bhh[128 + ch];
#pragma unroll
    for (int mt = 0; mt < 2; ++mt) {
#pragma unroll
        for (int reg = 0; reg < 4; ++reg) {
            int m = mt * 16 + lg * 4 + reg;
            float r  = sigm(accA[0][mt][reg] + bi0 + accB[0][mt][reg] + bh0);
            float zg = sigm(accA[1][mt][reg] + bi1 + accB[1][mt][reg] + bh1);
            float nn = tanhf(accA[2][mt][reg] + bi2 + r * (accB[2][mt][reg] + bh2));
            float xv = xbuf[(size_t)(node0 + m) * 64 + ch];
            xout[(size_t)(node0 + m) * 64 + ch] = (1.0f - zg) * nn + zg * xv;
        }
    }
}

// ---- MFMA transform: x = concat(x_prev, ze) @ tW + tb ----
__global__ __launch_bounds__(256) void trans_mfma_kernel(const float* __restrict__ xin,
                                                         const int* __restrict__ z,
                                                         const float* __restrict__ zemb_l,
                                                         const unsigned short* __restrict__ tWpk_l,
                                                         const float* __restrict__ tb,
                                                         float* __restrict__ xout) {
    __shared__ unsigned short a_lds[32][136];  // 128 + 8 pad
    int tid = threadIdx.x;
    int node0 = blockIdx.x * 32;

    const float4* x4 = (const float4*)(xin + (size_t)node0 * 64);
#pragma unroll
    for (int it = 0; it < 2; ++it) {
        int idx = it * 256 + tid;
        int r = idx >> 4, c4 = idx & 15;
        float4 v = x4[idx];
        ushort4 b; b.x = f2b(v.x); b.y = f2b(v.y); b.z = f2b(v.z); b.w = f2b(v.w);
        *(ushort4*)&a_lds[r][c4 * 4] = b;
    }
#pragma unroll
    for (int it = 0; it < 8; ++it) {
        int idx = it * 256 + tid;
        int n = idx >> 6, k = idx & 63;
        int z0 = z[(node0 + n) * 2], z1 = z[(node0 + n) * 2 + 1];
        float ze = zemb_l[z0 * 64 + k] + zemb_l[z1 * 64 + k];
        a_lds[n][64 + k] = f2b(ze);
    }
    __syncthreads();

    int lane = tid & 63, w = tid >> 6;
    int lr = lane & 15, lg = lane >> 4;

    f32x4 acc[2] = {};
#pragma unroll
    for (int t = 0; t < 4; ++t) {
        const unsigned short* pB = tWpk_l + ((size_t)(w * 4 + t) * 64 + lane) * 8;
        short8v bf = *(const short8v*)pB;
#pragma unroll
        for (int mt = 0; mt < 2; ++mt) {
            int row = mt * 16 + lr, koff = t * 32 + lg * 8;
            short8v af = *(const short8v*)&a_lds[row][koff];
            acc[mt] = __builtin_amdgcn_mfma_f32_16x16x32_bf16(af, bf, acc[mt], 0, 0, 0);
        }
    }
    int ch = w * 16 + lr;
    float tbc = tb[ch];
#pragma unroll
    for (int mt = 0; mt < 2; ++mt)
#pragma unroll
        for (int reg = 0; reg < 4; ++reg) {
            int m = mt * 16 + lg * 4 + reg;
            xout[(size_t)(node0 + m) * 64 + ch] = acc[mt][reg] + tbc;
        }
}

// ---- segment-sum pooling via atomics ----
__global__ void pool_kernel(const float* __restrict__ in, const int* __restrict__ idx,
                            float* __restrict__ out, int rows) {
    int i = blockIdx.x * 256 + threadIdx.x;
    if (i >= rows * 64) return;
    int r = i >> 6, c = i & 63;
    atomicAdd(out + (size_t)idx[r] * 64 + c, in[i]);
}

// ---- in-place MLP: buf = relu(buf@W1+b1)@W2+b2, 4 rows per block ----
__global__ __launch_bounds__(256) void mlp_kernel(float* __restrict__ buf,
                                                  const float* __restrict__ W1,
                                                  const float* __restrict__ b1,
                                                  const float* __restrict__ W2,
                                                  const float* __restrict__ b2) {
    __shared__ float in_t[4][64];
    __shared__ float h_t[4][64];
    int tid = threadIdx.x;
    int c = tid & 63, r = tid >> 6;
    int row0 = blockIdx.x * 4;
    in_t[r][c] = buf[(size_t)(row0 + r) * 64 + c];
    __syncthreads();
    float acc = b1[c];
    for (int k = 0; k < 64; ++k) acc = fmaf(in_t[r][k], W1[k * 64 + c], acc);
    h_t[r][c] = fmaxf(acc, 0.0f);
    __syncthreads();
    acc = b2[c];
    for (int k = 0; k < 64; ++k) acc = fmaf(h_t[r][k], W2[k * 64 + c], acc);
    buf[(size_t)(row0 + r) * 64 + c] = acc;
}

// ---- final: g[64,64] -> fc1(elu) -> fc2(elu) -> fc3 -> out[64] ----
__global__ __launch_bounds__(256) void final_kernel(const float* __restrict__ g,
                                                    const float* __restrict__ fc1W, const float* __restrict__ fc1b,
                                                    const float* __restrict__ fc2W, const float* __restrict__ fc2b,
                                                    const float* __restrict__ fc3W, const float* __restrict__ fc3b,
                                                    float* __restrict__ out) {
    __shared__ float gt[64][64];
    __shared__ float h1[64][32];
    __shared__ float h2[64][16];
    int tid = threadIdx.x;
    for (int i = tid; i < 64 * 64; i += 256) gt[i >> 6][i & 63] = g[i];
    __syncthreads();
    for (int i = tid; i < 64 * 32; i += 256) {
        int r = i >> 5, c = i & 31;
        float acc = fc1b[c];
        for (int k = 0; k < 64; ++k) acc = fmaf(gt[r][k], fc1W[k * 32 + c], acc);
        h1[r][c] = elu(acc);
    }
    __syncthreads();
    for (int i = tid; i < 64 * 16; i += 256) {
        int r = i >> 4, c = i & 15;
        float acc = fc2b[c];
        for (int k = 0; k < 32; ++k) acc = fmaf(h1[r][k], fc2W[k * 16 + c], acc);
        h2[r][c] = elu(acc);
    }
    __syncthreads();
    if (tid < 64) {
        float acc = fc3b[0];
        for (int k = 0; k < 16; ++k) acc = fmaf(h2[tid][k], fc3W[k], acc);
        out[tid] = acc;
    }
}

extern "C" void kernel_launch(void* const* d_in, const int* in_sizes, int n_in,
                              void* d_out, int out_size, void* d_ws, size_t ws_size,
                              hipStream_t stream) {
    const int*   z     = (const int*)d_in[0];
    const int*   ei    = (const int*)d_in[1];
    const int*   n2s2  = (const int*)d_in[2];
    const int*   s22s  = (const int*)d_in[3];
    const int*   s2g   = (const int*)d_in[4];
    const float* z_emb = (const float*)d_in[5];
    const float* tW    = (const float*)d_in[6];
    const float* tb    = (const float*)d_in[7];
    const float* convW = (const float*)d_in[8];
    const float* gWih  = (const float*)d_in[9];
    const float* gbih  = (const float*)d_in[10];
    const float* gWhh  = (const float*)d_in[11];
    const float* gbhh  = (const float*)d_in[12];
    const float* epW1  = (const float*)d_in[13];
    const float* epb1  = (const float*)d_in[14];
    const float* epW2  = (const float*)d_in[15];
    const float* epb2  = (const float*)d_in[16];
    const float* npW1  = (const float*)d_in[17];
    const float* npb1  = (const float*)d_in[18];
    const float* npW2  = (const float*)d_in[19];
    const float* npb2  = (const float*)d_in[20];
    const float* fc1W  = (const float*)d_in[21];
    const float* fc1b  = (const float*)d_in[22];
    const float* fc2W  = (const float*)d_in[23];
    const float* fc2b  = (const float*)d_in[24];
    const float* fc3W  = (const float*)d_in[25];
    const float* fc3b  = (const float*)d_in[26];

    const int* srcp = ei;
    const int* dstp = ei + E;

    float* xbuf   = (float*)d_ws;            // N*64
    float* sbuf   = xbuf + (size_t)N * D;    // N*64
    float* WihP   = sbuf + (size_t)N * D;    // L*64*192
    int*   rowptr = (int*)(WihP + L * 64 * 192);  // N+1
    int*   cursor = rowptr + (N + 1);             // N
    int*   counts = cursor + N;                   // N
    int*   colbuf = counts + N;                   // E
    int*   blocksum = colbuf + E;                 // SCAN_NB
    int*   blockoff = blocksum + SCAN_NB;         // SCAN_NB
    uintptr_t pal = (uintptr_t)(blockoff + SCAN_NB);
    pal = (pal + 15) & ~(uintptr_t)15;
    unsigned short* Wgpk = (unsigned short*)pal;          // L*2*12*2*64*8 = 122880 shorts
    unsigned short* tWpk = Wgpk + (size_t)L * 2 * 12 * 2 * 64 * 8;  // (L-1)*4*4*64*8 shorts
    // pooling overlays on xbuf (free after last GRU)
    float* sg2  = xbuf;                    // NSG2*64
    float* sg   = sg2 + (size_t)NSG2 * D;  // NSG*64
    float* gbuf = sg + (size_t)NSG * D;    // 64*64

    hipMemsetAsync(counts, 0, (size_t)N * sizeof(int), stream);

    prep_kernel<<<(L * 64 * 192 + 255) / 256, 256, 0, stream>>>(convW, gWih, WihP);
    packg_kernel<<<(L * 2 * 12 * 2 * 64 + 255) / 256, 256, 0, stream>>>(WihP, gWhh, Wgpk);
    packt_kernel<<<((L - 1) * 4 * 4 * 64 + 255) / 256, 256, 0, stream>>>(tW, tWpk);

    count_kernel<<<4096, 256, 0, stream>>>(dstp, counts);
    scan1_kernel<<<SCAN_NB, SCAN_BLK, 0, stream>>>(counts, blocksum);
    scan2_kernel<<<1, 128, 0, stream>>>(blocksum, blockoff);
    scan3_kernel<<<SCAN_NB, SCAN_BLK, 0, stream>>>(counts, blockoff, rowptr, cursor);
    scatter_kernel<<<4096, 256, 0, stream>>>(srcp, dstp, cursor, colbuf);

    embed_kernel<<<(N * D + 255) / 256, 256, 0, stream>>>(z, z_emb, xbuf);

    for (int l = 0; l < L; ++l) {
        if (l > 0) {
            trans_mfma_kernel<<<N / 32, 256, 0, stream>>>(
                sbuf, z, z_emb + (size_t)l * 100 * 64,
                tWpk + (size_t)(l - 1) * 4 * 4 * 64 * 8,
                tb + (size_t)(l - 1) * 64, xbuf);
        }
        aggregate_kernel<<<(N + 3) / 4, 256, 0, stream>>>(xbuf, rowptr, colbuf, sbuf);
        gru_mfma_kernel<<<N / 32, 256, 0, stream>>>(
            sbuf, xbuf,
            Wgpk + (size_t)l * 2 * 12 * 2 * 64 * 8,
            gbih + (size_t)l * 192, gbhh + (size_t)l * 192, sbuf);
    }

    // pooling chain: x_final lives in sbuf
    hipMemsetAsync(sg2, 0, (size_t)(NSG2 + NSG + NG) * D * sizeof(float), stream);
    pool_kernel<<<(N * D + 255) / 256, 256, 0, stream>>>(sbuf, n2s2, sg2, N);
    mlp_kernel<<<NSG2 / 4, 256, 0, stream>>>(sg2, epW1, epb1, epW2, epb2);
    pool_kernel<<<(NSG2 * D + 255) / 256, 256, 0, stream>>>(sg2, s22s, sg, NSG2);
    mlp_kernel<<<NSG / 4, 256, 0, stream>>>(sg, npW1, npb1, npW2, npb2);
    pool_kernel<<<(NSG * D + 255) / 256, 256, 0, stream>>>(sg, s2g, gbuf, NSG);
    final_kernel<<<1, 256, 0, stream>>>(gbuf, fc1W, fc1b, fc2W, fc2b, fc3W, fc3b, (float*)d_out);
}

// Round 5
// 655.102 us; speedup vs baseline: 3.0141x; 1.1175x over previous
//
#include <hip/hip_runtime.h>
#include <hip/hip_bf16.h>

constexpr int N    = 100000;
constexpr int E    = 1600000;
constexpr int NSG2 = 20000;
constexpr int NSG  = 2000;
constexpr int NG   = 64;
constexpr int D    = 64;
constexpr int L    = 5;

constexpr int SCAN_BLK = 1024;
constexpr int SCAN_NB  = (N + SCAN_BLK - 1) / SCAN_BLK;  // 98

constexpr int NPB   = 32;                 // nodes per bucket (N % NPB == 0)
constexpr int NBUCK = N / NPB;            // 3125
constexpr int BCAP  = 768;                // Poisson(512) + 11 sigma

typedef __attribute__((ext_vector_type(8))) short short8v;
typedef __attribute__((ext_vector_type(4))) float f32x4;

__device__ __forceinline__ float sigm(float x) { return 1.0f / (1.0f + expf(-x)); }
__device__ __forceinline__ float elu(float x)  { return x > 0.0f ? x : (expf(x) - 1.0f); }

__device__ __forceinline__ unsigned short f2b(float f) {
    union { float f; unsigned u; } x; x.f = f;
    unsigned r = (x.u + 0x7FFFu + ((x.u >> 16) & 1u)) >> 16;   // RNE
    return (unsigned short)r;
}

// ---- WihP[l] = conv_W[l] @ gru_Wih[l]  (64x64 @ 64x192) ----
__global__ __launch_bounds__(256) void prep_kernel(const float* __restrict__ convW,
                                                   const float* __restrict__ Wih,
                                                   float* __restrict__ WihP) {
    int idx = blockIdx.x * 256 + threadIdx.x;   // L*64*192 = 61440
    if (idx >= L * 64 * 192) return;
    int l = idx / (64 * 192);
    int rem = idx % (64 * 192);
    int i = rem / 192, j = rem % 192;
    const float* W  = convW + l * 64 * 64;
    const float* Wi = Wih  + l * 64 * 192;
    float acc = 0.0f;
    for (int t = 0; t < 64; ++t) acc = fmaf(W[i * 64 + t], Wi[t * 192 + j], acc);
    WihP[idx] = acc;
}

// ---- pack GRU weights into bf16 MFMA B-fragments ----
__global__ __launch_bounds__(256) void packg_kernel(const float* __restrict__ WihP,
                                                    const float* __restrict__ gWhh,
                                                    unsigned short* __restrict__ Wgpk) {
    int idx = blockIdx.x * 256 + threadIdx.x;
    if (idx >= L * 2 * 12 * 2 * 64) return;
    int lane = idx & 63;
    int r1 = idx >> 6;
    int t  = r1 & 1;
    int r2 = r1 >> 1;
    int nt = r2 % 12;
    int lm = r2 / 12;             // l*2+mat
    int mat = lm & 1, l = lm >> 1;
    const float* W = mat ? (gWhh + (size_t)l * 64 * 192) : (WihP + (size_t)l * 64 * 192);
    int n  = nt * 16 + (lane & 15);
    int k0 = t * 32 + (lane >> 4) * 8;
    short8v v;
#pragma unroll
    for (int j = 0; j < 8; ++j) v[j] = (short)f2b(W[(k0 + j) * 192 + n]);
    *(short8v*)(Wgpk + (size_t)idx * 8) = v;
}

// ---- pack transform weights ----
__global__ __launch_bounds__(256) void packt_kernel(const float* __restrict__ tW,
                                                    unsigned short* __restrict__ tWpk) {
    int idx = blockIdx.x * 256 + threadIdx.x;
    if (idx >= (L - 1) * 4 * 4 * 64) return;
    int lane = idx & 63;
    int r1 = idx >> 6;
    int t  = r1 & 3;
    int r2 = r1 >> 2;
    int nt = r2 & 3;
    int lm = r2 >> 2;
    const float* W = tW + (size_t)lm * 128 * 64;
    int n  = nt * 16 + (lane & 15);
    int k0 = t * 32 + (lane >> 4) * 8;
    short8v v;
#pragma unroll
    for (int j = 0; j < 8; ++j) v[j] = (short)f2b(W[(k0 + j) * 64 + n]);
    *(short8v*)(tWpk + (size_t)idx * 8) = v;
}

// ---- CSR build: bucketed two-phase ----
// Phase A: append (dloc<<17 | src) into per-bucket regions
__global__ void bucketA_kernel(const int* __restrict__ src, const int* __restrict__ dst,
                               int* __restrict__ bcnt, unsigned* __restrict__ tmp) {
    for (int e = blockIdx.x * blockDim.x + threadIdx.x; e < E; e += gridDim.x * blockDim.x) {
        int d = dst[e];
        int b = d >> 5;
        int pos = atomicAdd(&bcnt[b * 16], 1);     // 64B-strided counters
        if (pos < BCAP)
            tmp[(size_t)b * BCAP + pos] = ((unsigned)(d & 31) << 17) | (unsigned)src[e];
    }
}

// Phase B1: per-bucket LDS histogram -> counts (coalesced writes)
__global__ __launch_bounds__(256) void bucketB1_kernel(const unsigned* __restrict__ tmp,
                                                       const int* __restrict__ bcnt,
                                                       int* __restrict__ counts) {
    __shared__ int hist[NPB];
    int b = blockIdx.x;
    int tid = threadIdx.x;
    if (tid < NPB) hist[tid] = 0;
    __syncthreads();
    int cnt = min(bcnt[b * 16], BCAP);
    for (int i = tid; i < cnt; i += 256) {
        unsigned w = tmp[(size_t)b * BCAP + i];
        atomicAdd(&hist[w >> 17], 1);
    }
    __syncthreads();
    if (tid < NPB) counts[b * NPB + tid] = hist[tid];
}

// Phase B2: per-bucket LDS cursors -> col (localized writes)
__global__ __launch_bounds__(256) void bucketB2_kernel(const unsigned* __restrict__ tmp,
                                                       const int* __restrict__ bcnt,
                                                       const int* __restrict__ rowptr,
                                                       int* __restrict__ col) {
    __shared__ int cur[NPB];
    int b = blockIdx.x;
    int tid = threadIdx.x;
    if (tid < NPB) cur[tid] = rowptr[b * NPB + tid];
    __syncthreads();
    int cnt = min(bcnt[b * 16], BCAP);
    for (int i = tid; i < cnt; i += 256) {
        unsigned w = tmp[(size_t)b * BCAP + i];
        int pos = atomicAdd(&cur[w >> 17], 1);
        col[pos] = (int)(w & 0x1FFFFu);
    }
}

__global__ __launch_bounds__(1024) void scan1_kernel(const int* __restrict__ counts,
                                                     int* __restrict__ blocksum) {
    int i = blockIdx.x * SCAN_BLK + threadIdx.x;
    int v = (i < N) ? counts[i] : 0;
#pragma unroll
    for (int off = 32; off > 0; off >>= 1) v += __shfl_down(v, off, 64);
    __shared__ int ws[16];
    int wid = threadIdx.x >> 6, lane = threadIdx.x & 63;
    if (lane == 0) ws[wid] = v;
    __syncthreads();
    if (threadIdx.x == 0) {
        int s = 0;
#pragma unroll
        for (int w = 0; w < 16; ++w) s += ws[w];
        blocksum[blockIdx.x] = s;
    }
}

__global__ __launch_bounds__(128) void scan2_kernel(const int* __restrict__ blocksum,
                                                    int* __restrict__ blockoff) {
    __shared__ int sh[128];
    int t = threadIdx.x;
    int v = (t < SCAN_NB) ? blocksum[t] : 0;
    sh[t] = v;
    __syncthreads();
    for (int off = 1; off < 128; off <<= 1) {
        int u = (t >= off) ? sh[t - off] : 0;
        __syncthreads();
        sh[t] += u;
        __syncthreads();
    }
    if (t < SCAN_NB) blockoff[t] = sh[t] - v;  // exclusive
}

__global__ __launch_bounds__(1024) void scan3_kernel(const int* __restrict__ counts,
                                                     const int* __restrict__ blockoff,
                                                     int* __restrict__ rowptr) {
    int i = blockIdx.x * SCAN_BLK + threadIdx.x;
    int v = (i < N) ? counts[i] : 0;
    int lane = threadIdx.x & 63, wid = threadIdx.x >> 6;
    int sv = v;
#pragma unroll
    for (int off = 1; off < 64; off <<= 1) {
        int u = __shfl_up(sv, off, 64);
        if (lane >= off) sv += u;
    }
    __shared__ int wsum[16];
    if (lane == 63) wsum[wid] = sv;
    __syncthreads();
    if (threadIdx.x == 0) {
        int r = 0;
#pragma unroll
        for (int w = 0; w < 16; ++w) { int t = wsum[w]; wsum[w] = r; r += t; }
    }
    __syncthreads();
    int excl = sv - v + wsum[wid] + blockoff[blockIdx.x];
    if (i < N) rowptr[i] = excl;
    if (i == N - 1) rowptr[N] = excl + v;
}

// ---- x0 = z_emb[0][z].sum(1) ----
__global__ __launch_bounds__(256) void embed_kernel(const int* __restrict__ z,
                                                    const float* __restrict__ zemb0,
                                                    float* __restrict__ x) {
    int idx = blockIdx.x * 256 + threadIdx.x;  // N*64
    if (idx >= N * D) return;
    int n = idx >> 6, c = idx & 63;
    x[idx] = zemb0[z[n * 2] * 64 + c] + zemb0[z[n * 2 + 1] * 64 + c];
}

// ---- s[v] = sum_{e: dst==v} x[src[e]] : wave = 4 slots x 16 lanes, float4/lane, 4-deep ----
__global__ __launch_bounds__(256) void aggregate_kernel(const float* __restrict__ x,
                                                        const int* __restrict__ rowptr,
                                                        const int* __restrict__ col,
                                                        float* __restrict__ s) {
    int node = blockIdx.x * 4 + (threadIdx.x >> 6);
    int lane = threadIdx.x & 63;
    if (node >= N) return;
    int grp = lane >> 4;
    int cl  = lane & 15;
    int beg = rowptr[node], end = rowptr[node + 1];

    float ax = 0.f, ay = 0.f, az = 0.f, aw = 0.f;
    int i = beg + grp;
    for (; i + 12 < end; i += 16) {
        int u0 = col[i], u1 = col[i + 4], u2 = col[i + 8], u3 = col[i + 12];
        float4 v0 = ((const float4*)(x + (size_t)u0 * 64))[cl];
        float4 v1 = ((const float4*)(x + (size_t)u1 * 64))[cl];
        float4 v2 = ((const float4*)(x + (size_t)u2 * 64))[cl];
        float4 v3 = ((const float4*)(x + (size_t)u3 * 64))[cl];
        ax += (v0.x + v1.x) + (v2.x + v3.x);
        ay += (v0.y + v1.y) + (v2.y + v3.y);
        az += (v0.z + v1.z) + (v2.z + v3.z);
        aw += (v0.w + v1.w) + (v2.w + v3.w);
    }
    for (; i + 4 < end; i += 8) {
        int u0 = col[i], u1 = col[i + 4];
        float4 v0 = ((const float4*)(x + (size_t)u0 * 64))[cl];
        float4 v1 = ((const float4*)(x + (size_t)u1 * 64))[cl];
        ax += v0.x + v1.x; ay += v0.y + v1.y;
        az += v0.z + v1.z; aw += v0.w + v1.w;
    }
    if (i < end) {
        int u = col[i];
        float4 v = ((const float4*)(x + (size_t)u * 64))[cl];
        ax += v.x; ay += v.y; az += v.z; aw += v.w;
    }
#pragma unroll
    for (int off = 16; off < 64; off <<= 1) {
        ax += __shfl_xor(ax, off, 64);
        ay += __shfl_xor(ay, off, 64);
        az += __shfl_xor(az, off, 64);
        aw += __shfl_xor(aw, off, 64);
    }
    if (grp == 0) {
        float4 r; r.x = ax; r.y = ay; r.z = az; r.w = aw;
        ((float4*)(s + (size_t)node * 64))[cl] = r;
    }
}

// ---- MFMA GRU: 32 nodes/block, 4 waves; wave w owns channels [16w,16w+16) ----
__global__ __launch_bounds__(256) void gru_mfma_kernel(const float* __restrict__ sbuf,
                                                       const float* __restrict__ xbuf,
                                                       const unsigned short* __restrict__ Wgpk_l,
                                                       const float* __restrict__ bih,
                                                       const float* __restrict__ bhh,
                                                       float* __restrict__ xout) {
    __shared__ unsigned short s_lds[32][72];   // +8 pad
    __shared__ unsigned short x_lds[32][72];
    int tid = threadIdx.x;
    int node0 = blockIdx.x * 32;

    const float4* s4 = (const float4*)(sbuf + (size_t)node0 * 64);
    const float4* x4 = (const float4*)(xbuf + (size_t)node0 * 64);
#pragma unroll
    for (int it = 0; it < 2; ++it) {
        int idx = it * 256 + tid;
        int r = idx >> 4, c4 = idx & 15;
        float4 v = s4[idx];
        ushort4 b; b.x = f2b(v.x); b.y = f2b(v.y); b.z = f2b(v.z); b.w = f2b(v.w);
        *(ushort4*)&s_lds[r][c4 * 4] = b;
        float4 u = x4[idx];
        ushort4 b2; b2.x = f2b(u.x); b2.y = f2b(u.y); b2.z = f2b(u.z); b2.w = f2b(u.w);
        *(ushort4*)&x_lds[r][c4 * 4] = b2;
    }
    __syncthreads();

    int lane = tid & 63, w = tid >> 6;
    int lr = lane & 15, lg = lane >> 4;

    short8v as_[2][2], ax_[2][2];
#pragma unroll
    for (int mt = 0; mt < 2; ++mt)
#pragma unroll
        for (int t = 0; t < 2; ++t) {
            int row = mt * 16 + lr, koff = t * 32 + lg * 8;
            as_[mt][t] = *(const short8v*)&s_lds[row][koff];
            ax_[mt][t] = *(const short8v*)&x_lds[row][koff];
        }

    f32x4 accA[3][2] = {};  // gi [gate][mt]
    f32x4 accB[3][2] = {};  // gh
#pragma unroll
    for (int g = 0; g < 3; ++g) {
        int nt = g * 4 + w;
#pragma unroll
        for (int t = 0; t < 2; ++t) {
            const unsigned short* pA = Wgpk_l + ((size_t)((0 * 12 + nt) * 2 + t) * 64 + lane) * 8;
            const unsigned short* pB = Wgpk_l + ((size_t)((1 * 12 + nt) * 2 + t) * 64 + lane) * 8;
            short8v bA = *(const short8v*)pA;
            short8v bB = *(const short8v*)pB;
#pragma unroll
            for (int mt = 0; mt < 2; ++mt) {
                accA[g][mt] = __builtin_amdgcn_mfma_f32_16x16x32_bf16(as_[mt][t], bA, accA[g][mt], 0, 0, 0);
                accB[g][mt] = __builtin_amdgcn_mfma_f32_16x16x32_bf16(ax_[mt][t], bB, accB[g][mt], 0, 0, 0);
            }
        }
    }

    int ch = w * 16 + lr;
    float bi0 = bih[ch], bi1 = bih[64 + ch], bi2 = bih[128 + ch];
    float bh0 = bhh[ch], bh1 = bhh[64 + ch], bh2 = bhh[128 + ch];
#pragma unroll
    for (int mt = 0; mt < 2; ++mt) {
#pragma unroll
        for (int reg = 0; reg < 4; ++reg) {
            int m = mt * 16 + lg * 4 + reg;
            float r  = sigm(accA[0][mt][reg] + bi0 + accB[0][mt][reg] + bh0);
            float zg = sigm(accA[1][mt][reg] + bi1 + accB[1][mt][reg] + bh1);
            float nn = tanhf(accA[2][mt][reg] + bi2 + r * (accB[2][mt][reg] + bh2));
            float xv = xbuf[(size_t)(node0 + m) * 64 + ch];
            xout[(size_t)(node0 + m) * 64 + ch] = (1.0f - zg) * nn + zg * xv;
        }
    }
}

// ---- MFMA transform: x = concat(x_prev, ze) @ tW + tb ----
__global__ __launch_bounds__(256) void trans_mfma_kernel(const float* __restrict__ xin,
                                                         const int* __restrict__ z,
                                                         const float* __restrict__ zemb_l,
                                                         const unsigned short* __restrict__ tWpk_l,
                                                         const float* __restrict__ tb,
                                                         float* __restrict__ xout) {
    __shared__ unsigned short a_lds[32][136];  // 128 + 8 pad
    int tid = threadIdx.x;
    int node0 = blockIdx.x * 32;

    const float4* x4 = (const float4*)(xin + (size_t)node0 * 64);
#pragma unroll
    for (int it = 0; it < 2; ++it) {
        int idx = it * 256 + tid;
        int r = idx >> 4, c4 = idx & 15;
        float4 v = x4[idx];
        ushort4 b; b.x = f2b(v.x); b.y = f2b(v.y); b.z = f2b(v.z); b.w = f2b(v.w);
        *(ushort4*)&a_lds[r][c4 * 4] = b;
    }
#pragma unroll
    for (int it = 0; it < 8; ++it) {
        int idx = it * 256 + tid;
        int n = idx >> 6, k = idx & 63;
        int z0 = z[(node0 + n) * 2], z1 = z[(node0 + n) * 2 + 1];
        float ze = zemb_l[z0 * 64 + k] + zemb_l[z1 * 64 + k];
        a_lds[n][64 + k] = f2b(ze);
    }
    __syncthreads();

    int lane = tid & 63, w = tid >> 6;
    int lr = lane & 15, lg = lane >> 4;

    f32x4 acc[2] = {};
#pragma unroll
    for (int t = 0; t < 4; ++t) {
        const unsigned short* pB = tWpk_l + ((size_t)(w * 4 + t) * 64 + lane) * 8;
        short8v bf = *(const short8v*)pB;
#pragma unroll
        for (int mt = 0; mt < 2; ++mt) {
            int row = mt * 16 + lr, koff = t * 32 + lg * 8;
            short8v af = *(const short8v*)&a_lds[row][koff];
            acc[mt] = __builtin_amdgcn_mfma_f32_16x16x32_bf16(af, bf, acc[mt], 0, 0, 0);
        }
    }
    int ch = w * 16 + lr;
    float tbc = tb[ch];
#pragma unroll
    for (int mt = 0; mt < 2; ++mt)
#pragma unroll
        for (int reg = 0; reg < 4; ++reg) {
            int m = mt * 16 + lg * 4 + reg;
            xout[(size_t)(node0 + m) * 64 + ch] = acc[mt][reg] + tbc;
        }
}

// ---- segment-sum pooling via atomics ----
__global__ void pool_kernel(const float* __restrict__ in, const int* __restrict__ idx,
                            float* __restrict__ out, int rows) {
    int i = blockIdx.x * 256 + threadIdx.x;
    if (i >= rows * 64) return;
    int r = i >> 6, c = i & 63;
    atomicAdd(out + (size_t)idx[r] * 64 + c, in[i]);
}

// ---- in-place MLP: buf = relu(buf@W1+b1)@W2+b2, 4 rows per block ----
__global__ __launch_bounds__(256) void mlp_kernel(float* __restrict__ buf,
                                                  const float* __restrict__ W1,
                                                  const float* __restrict__ b1,
                                                  const float* __restrict__ W2,
                                                  const float* __restrict__ b2) {
    __shared__ float in_t[4][64];
    __shared__ float h_t[4][64];
    int tid = threadIdx.x;
    int c = tid & 63, r = tid >> 6;
    int row0 = blockIdx.x * 4;
    in_t[r][c] = buf[(size_t)(row0 + r) * 64 + c];
    __syncthreads();
    float acc = b1[c];
    for (int k = 0; k < 64; ++k) acc = fmaf(in_t[r][k], W1[k * 64 + c], acc);
    h_t[r][c] = fmaxf(acc, 0.0f);
    __syncthreads();
    acc = b2[c];
    for (int k = 0; k < 64; ++k) acc = fmaf(h_t[r][k], W2[k * 64 + c], acc);
    buf[(size_t)(row0 + r) * 64 + c] = acc;
}

// ---- final: g[64,64] -> fc1(elu) -> fc2(elu) -> fc3 -> out[64] ----
__global__ __launch_bounds__(256) void final_kernel(const float* __restrict__ g,
                                                    const float* __restrict__ fc1W, const float* __restrict__ fc1b,
                                                    const float* __restrict__ fc2W, const float* __restrict__ fc2b,
                                                    const float* __restrict__ fc3W, const float* __restrict__ fc3b,
                                                    float* __restrict__ out) {
    __shared__ float gt[64][64];
    __shared__ float h1[64][32];
    __shared__ float h2[64][16];
    int tid = threadIdx.x;
    for (int i = tid; i < 64 * 64; i += 256) gt[i >> 6][i & 63] = g[i];
    __syncthreads();
    for (int i = tid; i < 64 * 32; i += 256) {
        int r = i >> 5, c = i & 31;
        float acc = fc1b[c];
        for (int k = 0; k < 64; ++k) acc = fmaf(gt[r][k], fc1W[k * 32 + c], acc);
        h1[r][c] = elu(acc);
    }
    __syncthreads();
    for (int i = tid; i < 64 * 16; i += 256) {
        int r = i >> 4, c = i & 15;
        float acc = fc2b[c];
        for (int k = 0; k < 32; ++k) acc = fmaf(h1[r][k], fc2W[k * 16 + c], acc);
        h2[r][c] = elu(acc);
    }
    __syncthreads();
    if (tid < 64) {
        float acc = fc3b[0];
        for (int k = 0; k < 16; ++k) acc = fmaf(h2[tid][k], fc3W[k], acc);
        out[tid] = acc;
    }
}

extern "C" void kernel_launch(void* const* d_in, const int* in_sizes, int n_in,
                              void* d_out, int out_size, void* d_ws, size_t ws_size,
                              hipStream_t stream) {
    const int*   z     = (const int*)d_in[0];
    const int*   ei    = (const int*)d_in[1];
    const int*   n2s2  = (const int*)d_in[2];
    const int*   s22s  = (const int*)d_in[3];
    const int*   s2g   = (const int*)d_in[4];
    const float* z_emb = (const float*)d_in[5];
    const float* tW    = (const float*)d_in[6];
    const float* tb    = (const float*)d_in[7];
    const float* convW = (const float*)d_in[8];
    const float* gWih  = (const float*)d_in[9];
    const float* gbih  = (const float*)d_in[10];
    const float* gWhh  = (const float*)d_in[11];
    const float* gbhh  = (const float*)d_in[12];
    const float* epW1  = (const float*)d_in[13];
    const float* epb1  = (const float*)d_in[14];
    const float* epW2  = (const float*)d_in[15];
    const float* epb2  = (const float*)d_in[16];
    const float* npW1  = (const float*)d_in[17];
    const float* npb1  = (const float*)d_in[18];
    const float* npW2  = (const float*)d_in[19];
    const float* npb2  = (const float*)d_in[20];
    const float* fc1W  = (const float*)d_in[21];
    const float* fc1b  = (const float*)d_in[22];
    const float* fc2W  = (const float*)d_in[23];
    const float* fc2b  = (const float*)d_in[24];
    const float* fc3W  = (const float*)d_in[25];
    const float* fc3b  = (const float*)d_in[26];

    const int* srcp = ei;
    const int* dstp = ei + E;

    float* xbuf   = (float*)d_ws;            // N*64
    float* sbuf   = xbuf + (size_t)N * D;    // N*64
    float* WihP   = sbuf + (size_t)N * D;    // L*64*192
    int*   rowptr = (int*)(WihP + L * 64 * 192);  // N+1
    int*   counts = rowptr + (N + 1);             // N
    int*   colbuf = counts + N;                   // E
    int*   blocksum = colbuf + E;                 // SCAN_NB
    int*   blockoff = blocksum + SCAN_NB;         // SCAN_NB
    uintptr_t pal = (uintptr_t)(blockoff + SCAN_NB);
    pal = (pal + 15) & ~(uintptr_t)15;
    unsigned short* Wgpk = (unsigned short*)pal;          // L*2*12*2*64*8 shorts
    unsigned short* tWpk = Wgpk + (size_t)L * 2 * 12 * 2 * 64 * 8;  // (L-1)*4*4*64*8 shorts
    // CSR-build overlays on xbuf/sbuf (dead until embed_kernel)
    unsigned* tmp = (unsigned*)xbuf;                       // NBUCK*BCAP = 9.6 MB
    int* bcnt = (int*)(tmp + (size_t)NBUCK * BCAP);        // NBUCK*16 ints
    // pooling overlays on xbuf (free after last GRU)
    float* sg2  = xbuf;                    // NSG2*64
    float* sg   = sg2 + (size_t)NSG2 * D;  // NSG*64
    float* gbuf = sg + (size_t)NSG * D;    // 64*64

    hipMemsetAsync(bcnt, 0, (size_t)NBUCK * 16 * sizeof(int), stream);

    prep_kernel<<<(L * 64 * 192 + 255) / 256, 256, 0, stream>>>(convW, gWih, WihP);
    packg_kernel<<<(L * 2 * 12 * 2 * 64 + 255) / 256, 256, 0, stream>>>(WihP, gWhh, Wgpk);
    packt_kernel<<<((L - 1) * 4 * 4 * 64 + 255) / 256, 256, 0, stream>>>(tW, tWpk);

    bucketA_kernel<<<4096, 256, 0, stream>>>(srcp, dstp, bcnt, tmp);
    bucketB1_kernel<<<NBUCK, 256, 0, stream>>>(tmp, bcnt, counts);
    scan1_kernel<<<SCAN_NB, SCAN_BLK, 0, stream>>>(counts, blocksum);
    scan2_kernel<<<1, 128, 0, stream>>>(blocksum, blockoff);
    scan3_kernel<<<SCAN_NB, SCAN_BLK, 0, stream>>>(counts, blockoff, rowptr);
    bucketB2_kernel<<<NBUCK, 256, 0, stream>>>(tmp, bcnt, rowptr, colbuf);

    embed_kernel<<<(N * D + 255) / 256, 256, 0, stream>>>(z, z_emb, xbuf);

    for (int l = 0; l < L; ++l) {
        if (l > 0) {
            trans_mfma_kernel<<<N / 32, 256, 0, stream>>>(
                sbuf, z, z_emb + (size_t)l * 100 * 64,
                tWpk + (size_t)(l - 1) * 4 * 4 * 64 * 8,
                tb + (size_t)(l - 1) * 64, xbuf);
        }
        aggregate_kernel<<<(N + 3) / 4, 256, 0, stream>>>(xbuf, rowptr, colbuf, sbuf);
        gru_mfma_kernel<<<N / 32, 256, 0, stream>>>(
            sbuf, xbuf,
            Wgpk + (size_t)l * 2 * 12 * 2 * 64 * 8,
            gbih + (size_t)l * 192, gbhh + (size_t)l * 192, sbuf);
    }

    // pooling chain: x_final lives in sbuf
    hipMemsetAsync(sg2, 0, (size_t)(NSG2 + NSG + NG) * D * sizeof(float), stream);
    pool_kernel<<<(N * D + 255) / 256, 256, 0, stream>>>(sbuf, n2s2, sg2, N);
    mlp_kernel<<<NSG2 / 4, 256, 0, stream>>>(sg2, epW1, epb1, epW2, epb2);
    pool_kernel<<<(NSG2 * D + 255) / 256, 256, 0, stream>>>(sg2, s22s, sg, NSG2);
    mlp_kernel<<<NSG / 4, 256, 0, stream>>>(sg, npW1, npb1, npW2, npb2);
    pool_kernel<<<(NSG * D + 255) / 256, 256, 0, stream>>>(sg, s2g, gbuf, NSG);
    final_kernel<<<1, 256, 0, stream>>>(gbuf, fc1W, fc1b, fc2W, fc2b, fc3W, fc3b, (float*)d_out);
}

// Round 6
// 570.681 us; speedup vs baseline: 3.4599x; 1.1479x over previous
//
#include <hip/hip_runtime.h>
#include <hip/hip_bf16.h>

constexpr int N    = 100000;
constexpr int E    = 1600000;
constexpr int NSG2 = 20000;
constexpr int NSG  = 2000;
constexpr int NG   = 64;
constexpr int D    = 64;
constexpr int L    = 5;

constexpr int NPB   = 32;                 // nodes per bucket
constexpr int NBUCK = N / NPB;            // 3125
constexpr int NSTR  = 8;                  // stripes (≈XCDs)
constexpr int SCAP  = 128;                // per (bucket,stripe) cap: mean 64, +8 sigma

typedef __attribute__((ext_vector_type(8))) short short8v;
typedef __attribute__((ext_vector_type(4))) float f32x4;

__device__ __forceinline__ float sigm(float x) { return 1.0f / (1.0f + expf(-x)); }
__device__ __forceinline__ float elu(float x)  { return x > 0.0f ? x : (expf(x) - 1.0f); }

__device__ __forceinline__ unsigned short f2b(float f) {
    union { float f; unsigned u; } x; x.f = f;
    unsigned r = (x.u + 0x7FFFu + ((x.u >> 16) & 1u)) >> 16;   // RNE
    return (unsigned short)r;
}
__device__ __forceinline__ float b2f(unsigned short h) {
    union { unsigned u; float f; } x; x.u = (unsigned)h << 16;
    return x.f;
}

// ---- WihP[l] = conv_W[l] @ gru_Wih[l]  (64x64 @ 64x192) ----
__global__ __launch_bounds__(256) void prep_kernel(const float* __restrict__ convW,
                                                   const float* __restrict__ Wih,
                                                   float* __restrict__ WihP) {
    int idx = blockIdx.x * 256 + threadIdx.x;   // L*64*192 = 61440
    if (idx >= L * 64 * 192) return;
    int l = idx / (64 * 192);
    int rem = idx % (64 * 192);
    int i = rem / 192, j = rem % 192;
    const float* W  = convW + l * 64 * 64;
    const float* Wi = Wih  + l * 64 * 192;
    float acc = 0.0f;
    for (int t = 0; t < 64; ++t) acc = fmaf(W[i * 64 + t], Wi[t * 192 + j], acc);
    WihP[idx] = acc;
}

// ---- pack GRU weights into bf16 MFMA B-fragments ----
__global__ __launch_bounds__(256) void packg_kernel(const float* __restrict__ WihP,
                                                    const float* __restrict__ gWhh,
                                                    unsigned short* __restrict__ Wgpk) {
    int idx = blockIdx.x * 256 + threadIdx.x;
    if (idx >= L * 2 * 12 * 2 * 64) return;
    int lane = idx & 63;
    int r1 = idx >> 6;
    int t  = r1 & 1;
    int r2 = r1 >> 1;
    int nt = r2 % 12;
    int lm = r2 / 12;             // l*2+mat
    int mat = lm & 1, l = lm >> 1;
    const float* W = mat ? (gWhh + (size_t)l * 64 * 192) : (WihP + (size_t)l * 64 * 192);
    int n  = nt * 16 + (lane & 15);
    int k0 = t * 32 + (lane >> 4) * 8;
    short8v v;
#pragma unroll
    for (int j = 0; j < 8; ++j) v[j] = (short)f2b(W[(k0 + j) * 192 + n]);
    *(short8v*)(Wgpk + (size_t)idx * 8) = v;
}

// ---- pack transform weights ----
__global__ __launch_bounds__(256) void packt_kernel(const float* __restrict__ tW,
                                                    unsigned short* __restrict__ tWpk) {
    int idx = blockIdx.x * 256 + threadIdx.x;
    if (idx >= (L - 1) * 4 * 4 * 64) return;
    int lane = idx & 63;
    int r1 = idx >> 6;
    int t  = r1 & 3;
    int r2 = r1 >> 2;
    int nt = r2 & 3;
    int lm = r2 >> 2;
    const float* W = tW + (size_t)lm * 128 * 64;
    int n  = nt * 16 + (lane & 15);
    int k0 = t * 32 + (lane >> 4) * 8;
    short8v v;
#pragma unroll
    for (int j = 0; j < 8; ++j) v[j] = (short)f2b(W[(k0 + j) * 64 + n]);
    *(short8v*)(tWpk + (size_t)idx * 8) = v;
}

// ---- CSR build: striped bucket append (stripe = blockIdx&7 ≈ XCD-local lines) ----
__global__ void bucketA_kernel(const int* __restrict__ src, const int* __restrict__ dst,
                               int* __restrict__ bcnt, unsigned* __restrict__ tmp) {
    int stripe = blockIdx.x & (NSTR - 1);
    for (int e = blockIdx.x * blockDim.x + threadIdx.x; e < E; e += gridDim.x * blockDim.x) {
        int d = dst[e];
        int cell = (d >> 5) * NSTR + stripe;
        int pos = atomicAdd(&bcnt[cell * 16], 1);   // 64B-strided counters
        if (pos < SCAP)
            tmp[(size_t)cell * SCAP + pos] = ((unsigned)(d & 31) << 17) | (unsigned)src[e];
    }
}

// ---- scan of 3125 bucket totals -> bucket base offsets; also rowptr[N] ----
__global__ __launch_bounds__(1024) void bscan_kernel(const int* __restrict__ bcnt,
                                                     int* __restrict__ bbase,
                                                     int* __restrict__ rowptrN) {
    __shared__ int part[1024];
    int t = threadIdx.x;
    int loc[4]; int sum = 0;
#pragma unroll
    for (int j = 0; j < 4; ++j) {
        int b = t * 4 + j; int v = 0;
        if (b < NBUCK) {
#pragma unroll
            for (int s = 0; s < NSTR; ++s) v += min(bcnt[(b * NSTR + s) * 16], SCAP);
        }
        loc[j] = v; sum += v;
    }
    part[t] = sum;
    __syncthreads();
    for (int off = 1; off < 1024; off <<= 1) {
        int u = (t >= off) ? part[t - off] : 0;
        __syncthreads();
        part[t] += u;
        __syncthreads();
    }
    int run = part[t] - sum;
#pragma unroll
    for (int j = 0; j < 4; ++j) {
        int b = t * 4 + j;
        if (b < NBUCK) bbase[b] = run;
        run += loc[j];
    }
    if (t == 1023) { bbase[NBUCK] = part[1023]; rowptrN[0] = part[1023]; }
}

// ---- fused per-bucket: gather stripes -> LDS, histogram 32 nodes, scan -> rowptr, scatter -> col ----
__global__ __launch_bounds__(256) void bucketB_kernel(const unsigned* __restrict__ tmp,
                                                      const int* __restrict__ bcnt,
                                                      const int* __restrict__ bbase,
                                                      int* __restrict__ rowptr,
                                                      int* __restrict__ col) {
    __shared__ unsigned recs[NSTR * SCAP];   // 1024 * 4B
    __shared__ int scnt[NSTR];
    __shared__ int soff[NSTR + 1];
    __shared__ int cur[NPB];
    int b = blockIdx.x, tid = threadIdx.x;
    if (tid < NSTR) scnt[tid] = min(bcnt[(b * NSTR + tid) * 16], SCAP);
    if (tid < NPB) cur[tid] = 0;
    __syncthreads();
    if (tid == 0) {
        int r = 0;
        for (int s = 0; s < NSTR; ++s) { soff[s] = r; r += scnt[s]; }
        soff[NSTR] = r;
    }
    __syncthreads();
    int total = soff[NSTR];
    for (int i = tid; i < NSTR * SCAP; i += 256) {
        int s = i >> 7, k = i & (SCAP - 1);
        if (k < scnt[s]) recs[soff[s] + k] = tmp[((size_t)b * NSTR + s) * SCAP + k];
    }
    __syncthreads();
    for (int i = tid; i < total; i += 256) atomicAdd(&cur[recs[i] >> 17], 1);
    __syncthreads();
    if (tid == 0) {
        int base = bbase[b], r = 0;
        for (int j = 0; j < NPB; ++j) {
            int v = cur[j];
            cur[j] = base + r;
            rowptr[b * NPB + j] = base + r;
            r += v;
        }
    }
    __syncthreads();
    for (int i = tid; i < total; i += 256) {
        unsigned w = recs[i];
        int pos = atomicAdd(&cur[w >> 17], 1);
        col[pos] = (int)(w & 0x1FFFFu);
    }
}

// ---- x0 = z_emb[0][z].sum(1) -> fp32 + bf16 mirror ----
__global__ __launch_bounds__(256) void embed_kernel(const int* __restrict__ z,
                                                    const float* __restrict__ zemb0,
                                                    float* __restrict__ x,
                                                    unsigned short* __restrict__ xb) {
    int idx = blockIdx.x * 256 + threadIdx.x;  // N*64
    if (idx >= N * D) return;
    int n = idx >> 6, c = idx & 63;
    float v = zemb0[z[n * 2] * 64 + c] + zemb0[z[n * 2 + 1] * 64 + c];
    x[idx] = v;
    xb[idx] = f2b(v);
}

// ---- s[v] = sum bf16 x[src[e]] : wave = 8 slots x 8 lanes, bf16x8 (16B)/lane ----
__global__ __launch_bounds__(256) void aggregate_kernel(const unsigned short* __restrict__ xb,
                                                        const int* __restrict__ rowptr,
                                                        const int* __restrict__ col,
                                                        unsigned short* __restrict__ sb) {
    int node = blockIdx.x * 4 + (threadIdx.x >> 6);
    int lane = threadIdx.x & 63;
    if (node >= N) return;
    int grp = lane >> 3;   // neighbor slot 0..7
    int cl  = lane & 7;    // bf16x8 unit within row
    int beg = rowptr[node], end = rowptr[node + 1];

    float a[8] = {};
    int i = beg + grp;
    for (; i + 8 < end; i += 16) {
        int u0 = col[i], u1 = col[i + 8];
        short8v v0 = *(const short8v*)(xb + (size_t)u0 * 64 + cl * 8);
        short8v v1 = *(const short8v*)(xb + (size_t)u1 * 64 + cl * 8);
#pragma unroll
        for (int j = 0; j < 8; ++j)
            a[j] += b2f((unsigned short)v0[j]) + b2f((unsigned short)v1[j]);
    }
    if (i < end) {
        int u = col[i];
        short8v v = *(const short8v*)(xb + (size_t)u * 64 + cl * 8);
#pragma unroll
        for (int j = 0; j < 8; ++j) a[j] += b2f((unsigned short)v[j]);
    }
#pragma unroll
    for (int off = 8; off < 64; off <<= 1)
#pragma unroll
        for (int j = 0; j < 8; ++j) a[j] += __shfl_xor(a[j], off, 64);
    if (grp == 0) {
        short8v r;
#pragma unroll
        for (int j = 0; j < 8; ++j) r[j] = (short)f2b(a[j]);
        *(short8v*)(sb + (size_t)node * 64 + cl * 8) = r;
    }
}

// ---- MFMA GRU: 32 nodes/block, 4 waves; wave w owns channels [16w,16w+16) ----
__global__ __launch_bounds__(256) void gru_mfma_kernel(const unsigned short* __restrict__ sb,
                                                       float* __restrict__ xbuf,
                                                       unsigned short* __restrict__ xb,
                                                       const unsigned short* __restrict__ Wgpk_l,
                                                       const float* __restrict__ bih,
                                                       const float* __restrict__ bhh) {
    __shared__ unsigned short s_lds[32][72];   // row stride 144B (divisible by 16)
    __shared__ unsigned short x_lds[32][72];
    int tid = threadIdx.x;
    int node0 = blockIdx.x * 32;

    {   // pure bf16 copies, no conversion
        const float4* sb4 = (const float4*)(sb + (size_t)node0 * 64);
        const float4* xb4 = (const float4*)(xb + (size_t)node0 * 64);
        int r = tid >> 3, u = tid & 7;
        *(float4*)&s_lds[r][u * 8] = sb4[tid];
        *(float4*)&x_lds[r][u * 8] = xb4[tid];
    }
    __syncthreads();

    int lane = tid & 63, w = tid >> 6;
    int lr = lane & 15, lg = lane >> 4;

    short8v as_[2][2], ax_[2][2];
#pragma unroll
    for (int mt = 0; mt < 2; ++mt)
#pragma unroll
        for (int t = 0; t < 2; ++t) {
            int row = mt * 16 + lr, koff = t * 32 + lg * 8;
            as_[mt][t] = *(const short8v*)&s_lds[row][koff];
            ax_[mt][t] = *(const short8v*)&x_lds[row][koff];
        }

    f32x4 accA[3][2] = {};  // gi [gate][mt]
    f32x4 accB[3][2] = {};  // gh
#pragma unroll
    for (int g = 0; g < 3; ++g) {
        int nt = g * 4 + w;
#pragma unroll
        for (int t = 0; t < 2; ++t) {
            const unsigned short* pA = Wgpk_l + ((size_t)((0 * 12 + nt) * 2 + t) * 64 + lane) * 8;
            const unsigned short* pB = Wgpk_l + ((size_t)((1 * 12 + nt) * 2 + t) * 64 + lane) * 8;
            short8v bA = *(const short8v*)pA;
            short8v bB = *(const short8v*)pB;
#pragma unroll
            for (int mt = 0; mt < 2; ++mt) {
                accA[g][mt] = __builtin_amdgcn_mfma_f32_16x16x32_bf16(as_[mt][t], bA, accA[g][mt], 0, 0, 0);
                accB[g][mt] = __builtin_amdgcn_mfma_f32_16x16x32_bf16(ax_[mt][t], bB, accB[g][mt], 0, 0, 0);
            }
        }
    }

    int ch = w * 16 + lr;
    float bi0 = bih[ch], bi1 = bih[64 + ch], bi2 = bih[128 + ch];
    float bh0 = bhh[ch], bh1 = bhh[64 + ch], bh2 = bhh[128 + ch];
#pragma unroll
    for (int mt = 0; mt < 2; ++mt) {
#pragma unroll
        for (int reg = 0; reg < 4; ++reg) {
            int m = mt * 16 + lg * 4 + reg;
            float r  = sigm(accA[0][mt][reg] + bi0 + accB[0][mt][reg] + bh0);
            float zg = sigm(accA[1][mt][reg] + bi1 + accB[1][mt][reg] + bh1);
            float nn = tanhf(accA[2][mt][reg] + bi2 + r * (accB[2][mt][reg] + bh2));
            size_t o = (size_t)(node0 + m) * 64 + ch;
            float xo = (1.0f - zg) * nn + zg * xbuf[o];
            xbuf[o] = xo;
            xb[o] = f2b(xo);
        }
    }
}

// ---- MFMA transform: x = concat(x_prev, ze) @ tW + tb (in-place on xbuf/xb) ----
__global__ __launch_bounds__(256) void trans_mfma_kernel(const int* __restrict__ z,
                                                         const float* __restrict__ zemb_l,
                                                         const unsigned short* __restrict__ tWpk_l,
                                                         const float* __restrict__ tb,
                                                         float* __restrict__ xbuf,
                                                         unsigned short* __restrict__ xb) {
    __shared__ unsigned short a_lds[32][136];  // row stride 272B (divisible by 16)
    int tid = threadIdx.x;
    int node0 = blockIdx.x * 32;

    {   // x_prev from bf16 mirror, pure copy
        const float4* xb4 = (const float4*)(xb + (size_t)node0 * 64);
        int r = tid >> 3, u = tid & 7;
        *(float4*)&a_lds[r][u * 8] = xb4[tid];
    }
#pragma unroll
    for (int it = 0; it < 8; ++it) {
        int idx = it * 256 + tid;
        int n = idx >> 6, k = idx & 63;
        int z0 = z[(node0 + n) * 2], z1 = z[(node0 + n) * 2 + 1];
        float ze = zemb_l[z0 * 64 + k] + zemb_l[z1 * 64 + k];
        a_lds[n][64 + k] = f2b(ze);
    }
    __syncthreads();

    int lane = tid & 63, w = tid >> 6;
    int lr = lane & 15, lg = lane >> 4;

    f32x4 acc[2] = {};
#pragma unroll
    for (int t = 0; t < 4; ++t) {
        const unsigned short* pB = tWpk_l + ((size_t)(w * 4 + t) * 64 + lane) * 8;
        short8v bf = *(const short8v*)pB;
#pragma unroll
        for (int mt = 0; mt < 2; ++mt) {
            int row = mt * 16 + lr, koff = t * 32 + lg * 8;
            short8v af = *(const short8v*)&a_lds[row][koff];
            acc[mt] = __builtin_amdgcn_mfma_f32_16x16x32_bf16(af, bf, acc[mt], 0, 0, 0);
        }
    }
    int ch = w * 16 + lr;
    float tbc = tb[ch];
#pragma unroll
    for (int mt = 0; mt < 2; ++mt)
#pragma unroll
        for (int reg = 0; reg < 4; ++reg) {
            int m = mt * 16 + lg * 4 + reg;
            size_t o = (size_t)(node0 + m) * 64 + ch;
            float v = acc[mt][reg] + tbc;
            xbuf[o] = v;
            xb[o] = f2b(v);
        }
}

// ---- segment-sum pooling via atomics ----
__global__ void pool_kernel(const float* __restrict__ in, const int* __restrict__ idx,
                            float* __restrict__ out, int rows) {
    int i = blockIdx.x * 256 + threadIdx.x;
    if (i >= rows * 64) return;
    int r = i >> 6, c = i & 63;
    atomicAdd(out + (size_t)idx[r] * 64 + c, in[i]);
}

// ---- in-place MLP: buf = relu(buf@W1+b1)@W2+b2, 4 rows per block ----
__global__ __launch_bounds__(256) void mlp_kernel(float* __restrict__ buf,
                                                  const float* __restrict__ W1,
                                                  const float* __restrict__ b1,
                                                  const float* __restrict__ W2,
                                                  const float* __restrict__ b2) {
    __shared__ float in_t[4][64];
    __shared__ float h_t[4][64];
    int tid = threadIdx.x;
    int c = tid & 63, r = tid >> 6;
    int row0 = blockIdx.x * 4;
    in_t[r][c] = buf[(size_t)(row0 + r) * 64 + c];
    __syncthreads();
    float acc = b1[c];
    for (int k = 0; k < 64; ++k) acc = fmaf(in_t[r][k], W1[k * 64 + c], acc);
    h_t[r][c] = fmaxf(acc, 0.0f);
    __syncthreads();
    acc = b2[c];
    for (int k = 0; k < 64; ++k) acc = fmaf(h_t[r][k], W2[k * 64 + c], acc);
    buf[(size_t)(row0 + r) * 64 + c] = acc;
}

// ---- final: g[64,64] -> fc1(elu) -> fc2(elu) -> fc3 -> out[64] ----
__global__ __launch_bounds__(256) void final_kernel(const float* __restrict__ g,
                                                    const float* __restrict__ fc1W, const float* __restrict__ fc1b,
                                                    const float* __restrict__ fc2W, const float* __restrict__ fc2b,
                                                    const float* __restrict__ fc3W, const float* __restrict__ fc3b,
                                                    float* __restrict__ out) {
    __shared__ float gt[64][64];
    __shared__ float h1[64][32];
    __shared__ float h2[64][16];
    int tid = threadIdx.x;
    for (int i = tid; i < 64 * 64; i += 256) gt[i >> 6][i & 63] = g[i];
    __syncthreads();
    for (int i = tid; i < 64 * 32; i += 256) {
        int r = i >> 5, c = i & 31;
        float acc = fc1b[c];
        for (int k = 0; k < 64; ++k) acc = fmaf(gt[r][k], fc1W[k * 32 + c], acc);
        h1[r][c] = elu(acc);
    }
    __syncthreads();
    for (int i = tid; i < 64 * 16; i += 256) {
        int r = i >> 4, c = i & 15;
        float acc = fc2b[c];
        for (int k = 0; k < 32; ++k) acc = fmaf(h1[r][k], fc2W[k * 16 + c], acc);
        h2[r][c] = elu(acc);
    }
    __syncthreads();
    if (tid < 64) {
        float acc = fc3b[0];
        for (int k = 0; k < 16; ++k) acc = fmaf(h2[tid][k], fc3W[k], acc);
        out[tid] = acc;
    }
}

extern "C" void kernel_launch(void* const* d_in, const int* in_sizes, int n_in,
                              void* d_out, int out_size, void* d_ws, size_t ws_size,
                              hipStream_t stream) {
    const int*   z     = (const int*)d_in[0];
    const int*   ei    = (const int*)d_in[1];
    const int*   n2s2  = (const int*)d_in[2];
    const int*   s22s  = (const int*)d_in[3];
    const int*   s2g   = (const int*)d_in[4];
    const float* z_emb = (const float*)d_in[5];
    const float* tW    = (const float*)d_in[6];
    const float* tb    = (const float*)d_in[7];
    const float* convW = (const float*)d_in[8];
    const float* gWih  = (const float*)d_in[9];
    const float* gbih  = (const float*)d_in[10];
    const float* gWhh  = (const float*)d_in[11];
    const float* gbhh  = (const float*)d_in[12];
    const float* epW1  = (const float*)d_in[13];
    const float* epb1  = (const float*)d_in[14];
    const float* epW2  = (const float*)d_in[15];
    const float* epb2  = (const float*)d_in[16];
    const float* npW1  = (const float*)d_in[17];
    const float* npb1  = (const float*)d_in[18];
    const float* npW2  = (const float*)d_in[19];
    const float* npb2  = (const float*)d_in[20];
    const float* fc1W  = (const float*)d_in[21];
    const float* fc1b  = (const float*)d_in[22];
    const float* fc2W  = (const float*)d_in[23];
    const float* fc2b  = (const float*)d_in[24];
    const float* fc3W  = (const float*)d_in[25];
    const float* fc3b  = (const float*)d_in[26];

    const int* srcp = ei;
    const int* dstp = ei + E;

    float*          xbuf = (float*)d_ws;                          // N*64 f32
    unsigned short* xb   = (unsigned short*)(xbuf + (size_t)N * D);  // N*64 bf16 mirror
    unsigned short* sb   = xb + (size_t)N * D;                    // N*64 bf16 (aggregate out)
    float*          WihP = (float*)(sb + (size_t)N * D);          // L*64*192
    int*            rowptr = (int*)(WihP + L * 64 * 192);         // N+1
    int*            colbuf = rowptr + (N + 1);                    // E
    int*            bbase  = colbuf + E;                          // NBUCK+1
    uintptr_t pal = (uintptr_t)(bbase + NBUCK + 1);
    pal = (pal + 15) & ~(uintptr_t)15;
    unsigned short* Wgpk = (unsigned short*)pal;                  // L*2*12*2*64*8 shorts
    unsigned short* tWpk = Wgpk + (size_t)L * 2 * 12 * 2 * 64 * 8;
    // CSR-build overlays on xbuf region (dead until embed): 12.8MB + 1.6MB < 25.6MB
    unsigned* tmp  = (unsigned*)xbuf;                             // NBUCK*NSTR*SCAP u32
    int*      bcnt = (int*)(tmp + (size_t)NBUCK * NSTR * SCAP);   // NBUCK*NSTR*16 ints
    // pooling overlays on colbuf (dead after last aggregate): 5.65MB < 6.4MB
    float* sg2  = (float*)colbuf;          // NSG2*64
    float* sg   = sg2 + (size_t)NSG2 * D;  // NSG*64
    float* gbuf = sg + (size_t)NSG * D;    // 64*64

    hipMemsetAsync(bcnt, 0, (size_t)NBUCK * NSTR * 16 * sizeof(int), stream);

    prep_kernel<<<(L * 64 * 192 + 255) / 256, 256, 0, stream>>>(convW, gWih, WihP);
    packg_kernel<<<(L * 2 * 12 * 2 * 64 + 255) / 256, 256, 0, stream>>>(WihP, gWhh, Wgpk);
    packt_kernel<<<((L - 1) * 4 * 4 * 64 + 255) / 256, 256, 0, stream>>>(tW, tWpk);

    bucketA_kernel<<<4096, 256, 0, stream>>>(srcp, dstp, bcnt, tmp);
    bscan_kernel<<<1, 1024, 0, stream>>>(bcnt, bbase, rowptr + N);
    bucketB_kernel<<<NBUCK, 256, 0, stream>>>(tmp, bcnt, bbase, rowptr, colbuf);

    embed_kernel<<<(N * D + 255) / 256, 256, 0, stream>>>(z, z_emb, xbuf, xb);

    for (int l = 0; l < L; ++l) {
        if (l > 0) {
            trans_mfma_kernel<<<N / 32, 256, 0, stream>>>(
                z, z_emb + (size_t)l * 100 * 64,
                tWpk + (size_t)(l - 1) * 4 * 4 * 64 * 8,
                tb + (size_t)(l - 1) * 64, xbuf, xb);
        }
        aggregate_kernel<<<(N + 3) / 4, 256, 0, stream>>>(xb, rowptr, colbuf, sb);
        gru_mfma_kernel<<<N / 32, 256, 0, stream>>>(
            sb, xbuf, xb,
            Wgpk + (size_t)l * 2 * 12 * 2 * 64 * 8,
            gbih + (size_t)l * 192, gbhh + (size_t)l * 192);
    }

    // pooling chain: final x lives in xbuf (fp32)
    hipMemsetAsync(sg2, 0, (size_t)(NSG2 + NSG + NG) * D * sizeof(float), stream);
    pool_kernel<<<(N * D + 255) / 256, 256, 0, stream>>>(xbuf, n2s2, sg2, N);
    mlp_kernel<<<NSG2 / 4, 256, 0, stream>>>(sg2, epW1, epb1, epW2, epb2);
    pool_kernel<<<(NSG2 * D + 255) / 256, 256, 0, stream>>>(sg2, s22s, sg, NSG2);
    mlp_kernel<<<NSG / 4, 256, 0, stream>>>(sg, npW1, npb1, npW2, npb2);
    pool_kernel<<<(NSG * D + 255) / 256, 256, 0, stream>>>(sg, s2g, gbuf, NSG);
    final_kernel<<<1, 256, 0, stream>>>(gbuf, fc1W, fc1b, fc2W, fc2b, fc3W, fc3b, (float*)d_out);
}

// Round 7
// 555.125 us; speedup vs baseline: 3.5569x; 1.0280x over previous
//
#include <hip/hip_runtime.h>
#include <hip/hip_bf16.h>

constexpr int N    = 100000;
constexpr int E    = 1600000;
constexpr int NSG2 = 20000;
constexpr int NSG  = 2000;
constexpr int NG   = 64;
constexpr int D    = 64;
constexpr int L    = 5;

constexpr int NPB   = 32;                 // nodes per bucket
constexpr int NBUCK = N / NPB;            // 3125
constexpr int NSTR  = 8;                  // stripes (≈XCDs)
constexpr int SCAP  = 128;                // per (bucket,stripe) cap

typedef __attribute__((ext_vector_type(8))) short short8v;
typedef __attribute__((ext_vector_type(4))) float f32x4;

__device__ __forceinline__ float sigm(float x) { return 1.0f / (1.0f + expf(-x)); }
__device__ __forceinline__ float elu(float x)  { return x > 0.0f ? x : (expf(x) - 1.0f); }

__device__ __forceinline__ unsigned short f2b(float f) {
    union { float f; unsigned u; } x; x.f = f;
    unsigned r = (x.u + 0x7FFFu + ((x.u >> 16) & 1u)) >> 16;   // RNE
    return (unsigned short)r;
}
__device__ __forceinline__ float b2f(unsigned short h) {
    union { unsigned u; float f; } x; x.u = (unsigned)h << 16;
    return x.f;
}

// ---- WihP[l] = conv_W[l] @ gru_Wih[l]  (64x64 @ 64x192) ----
__global__ __launch_bounds__(256) void prep_kernel(const float* __restrict__ convW,
                                                   const float* __restrict__ Wih,
                                                   float* __restrict__ WihP) {
    int idx = blockIdx.x * 256 + threadIdx.x;   // L*64*192 = 61440
    if (idx >= L * 64 * 192) return;
    int l = idx / (64 * 192);
    int rem = idx % (64 * 192);
    int i = rem / 192, j = rem % 192;
    const float* W  = convW + l * 64 * 64;
    const float* Wi = Wih  + l * 64 * 192;
    float acc = 0.0f;
    for (int t = 0; t < 64; ++t) acc = fmaf(W[i * 64 + t], Wi[t * 192 + j], acc);
    WihP[idx] = acc;
}

// ---- pack GRU weights into bf16 MFMA B-fragments ----
__global__ __launch_bounds__(256) void packg_kernel(const float* __restrict__ WihP,
                                                    const float* __restrict__ gWhh,
                                                    unsigned short* __restrict__ Wgpk) {
    int idx = blockIdx.x * 256 + threadIdx.x;
    if (idx >= L * 2 * 12 * 2 * 64) return;
    int lane = idx & 63;
    int r1 = idx >> 6;
    int t  = r1 & 1;
    int r2 = r1 >> 1;
    int nt = r2 % 12;
    int lm = r2 / 12;             // l*2+mat
    int mat = lm & 1, l = lm >> 1;
    const float* W = mat ? (gWhh + (size_t)l * 64 * 192) : (WihP + (size_t)l * 64 * 192);
    int n  = nt * 16 + (lane & 15);
    int k0 = t * 32 + (lane >> 4) * 8;
    short8v v;
#pragma unroll
    for (int j = 0; j < 8; ++j) v[j] = (short)f2b(W[(k0 + j) * 192 + n]);
    *(short8v*)(Wgpk + (size_t)idx * 8) = v;
}

// ---- pack transform weights ----
__global__ __launch_bounds__(256) void packt_kernel(const float* __restrict__ tW,
                                                    unsigned short* __restrict__ tWpk) {
    int idx = blockIdx.x * 256 + threadIdx.x;
    if (idx >= (L - 1) * 4 * 4 * 64) return;
    int lane = idx & 63;
    int r1 = idx >> 6;
    int t  = r1 & 3;
    int r2 = r1 >> 2;
    int nt = r2 & 3;
    int lm = r2 >> 2;
    const float* W = tW + (size_t)lm * 128 * 64;
    int n  = nt * 16 + (lane & 15);
    int k0 = t * 32 + (lane >> 4) * 8;
    short8v v;
#pragma unroll
    for (int j = 0; j < 8; ++j) v[j] = (short)f2b(W[(k0 + j) * 64 + n]);
    *(short8v*)(tWpk + (size_t)idx * 8) = v;
}

// ---- CSR build: striped bucket append ----
__global__ void bucketA_kernel(const int* __restrict__ src, const int* __restrict__ dst,
                               int* __restrict__ bcnt, unsigned* __restrict__ tmp) {
    int stripe = blockIdx.x & (NSTR - 1);
    for (int e = blockIdx.x * blockDim.x + threadIdx.x; e < E; e += gridDim.x * blockDim.x) {
        int d = dst[e];
        int cell = (d >> 5) * NSTR + stripe;
        int pos = atomicAdd(&bcnt[cell * 16], 1);   // 64B-strided counters
        if (pos < SCAP)
            tmp[(size_t)cell * SCAP + pos] = ((unsigned)(d & 31) << 17) | (unsigned)src[e];
    }
}

__global__ __launch_bounds__(1024) void bscan_kernel(const int* __restrict__ bcnt,
                                                     int* __restrict__ bbase,
                                                     int* __restrict__ rowptrN) {
    __shared__ int part[1024];
    int t = threadIdx.x;
    int loc[4]; int sum = 0;
#pragma unroll
    for (int j = 0; j < 4; ++j) {
        int b = t * 4 + j; int v = 0;
        if (b < NBUCK) {
#pragma unroll
            for (int s = 0; s < NSTR; ++s) v += min(bcnt[(b * NSTR + s) * 16], SCAP);
        }
        loc[j] = v; sum += v;
    }
    part[t] = sum;
    __syncthreads();
    for (int off = 1; off < 1024; off <<= 1) {
        int u = (t >= off) ? part[t - off] : 0;
        __syncthreads();
        part[t] += u;
        __syncthreads();
    }
    int run = part[t] - sum;
#pragma unroll
    for (int j = 0; j < 4; ++j) {
        int b = t * 4 + j;
        if (b < NBUCK) bbase[b] = run;
        run += loc[j];
    }
    if (t == 1023) { bbase[NBUCK] = part[1023]; rowptrN[0] = part[1023]; }
}

// ---- fused per-bucket: stripes -> LDS, histogram, scan -> rowptr, scatter -> col ----
__global__ __launch_bounds__(256) void bucketB_kernel(const unsigned* __restrict__ tmp,
                                                      const int* __restrict__ bcnt,
                                                      const int* __restrict__ bbase,
                                                      int* __restrict__ rowptr,
                                                      int* __restrict__ col) {
    __shared__ unsigned recs[NSTR * SCAP];
    __shared__ int scnt[NSTR];
    __shared__ int soff[NSTR + 1];
    __shared__ int cur[NPB];
    int b = blockIdx.x, tid = threadIdx.x;
    if (tid < NSTR) scnt[tid] = min(bcnt[(b * NSTR + tid) * 16], SCAP);
    if (tid < NPB) cur[tid] = 0;
    __syncthreads();
    if (tid == 0) {
        int r = 0;
        for (int s = 0; s < NSTR; ++s) { soff[s] = r; r += scnt[s]; }
        soff[NSTR] = r;
    }
    __syncthreads();
    int total = soff[NSTR];
    for (int i = tid; i < NSTR * SCAP; i += 256) {
        int s = i >> 7, k = i & (SCAP - 1);
        if (k < scnt[s]) recs[soff[s] + k] = tmp[((size_t)b * NSTR + s) * SCAP + k];
    }
    __syncthreads();
    for (int i = tid; i < total; i += 256) atomicAdd(&cur[recs[i] >> 17], 1);
    __syncthreads();
    if (tid == 0) {
        int base = bbase[b], r = 0;
        for (int j = 0; j < NPB; ++j) {
            int v = cur[j];
            cur[j] = base + r;
            rowptr[b * NPB + j] = base + r;
            r += v;
        }
    }
    __syncthreads();
    for (int i = tid; i < total; i += 256) {
        unsigned w = recs[i];
        int pos = atomicAdd(&cur[w >> 17], 1);
        col[pos] = (int)(w & 0x1FFFFu);
    }
}

// ---- x0 = z_emb[0][z].sum(1) -> fp32 + bf16 mirror (float4) ----
__global__ __launch_bounds__(256) void embed_kernel(const int* __restrict__ z,
                                                    const float* __restrict__ zemb0,
                                                    float* __restrict__ x,
                                                    unsigned short* __restrict__ xb) {
    int idx = blockIdx.x * 256 + threadIdx.x;  // N*16 float4 units
    if (idx >= N * 16) return;
    int n = idx >> 4, k4 = idx & 15;
    float4 e0 = ((const float4*)(zemb0 + (size_t)z[n * 2] * 64))[k4];
    float4 e1 = ((const float4*)(zemb0 + (size_t)z[n * 2 + 1] * 64))[k4];
    float4 v; v.x = e0.x + e1.x; v.y = e0.y + e1.y; v.z = e0.z + e1.z; v.w = e0.w + e1.w;
    ((float4*)x)[idx] = v;
    ushort4 b; b.x = f2b(v.x); b.y = f2b(v.y); b.z = f2b(v.z); b.w = f2b(v.w);
    ((ushort4*)xb)[idx] = b;
}

// ---- fused layer: aggregate (gather) -> GRU MFMA -> [transform MFMA] ----
// block = 32 nodes, 4 waves. Aggregate: 8-lane group per node, no shuffles.
// HAS_T: also applies next layer's transform (concat with ze) in-block.
template<int HAS_T>
__global__ __launch_bounds__(256) void fused_kernel(const unsigned short* __restrict__ xb_in,
                                                    float* __restrict__ xbuf,
                                                    unsigned short* __restrict__ xb_out,
                                                    const int* __restrict__ rowptr,
                                                    const int* __restrict__ col,
                                                    const unsigned short* __restrict__ Wgpk_l,
                                                    const float* __restrict__ bih,
                                                    const float* __restrict__ bhh,
                                                    const int* __restrict__ z,
                                                    const float* __restrict__ zemb_next,
                                                    const unsigned short* __restrict__ tWpk_next,
                                                    const float* __restrict__ tb_next) {
    __shared__ unsigned short s_lds[32][72];
    __shared__ unsigned short x_lds[32][72];
    __shared__ unsigned short a_lds[32][136];
    int tid = threadIdx.x;
    int node0 = blockIdx.x * 32;
    int lane = tid & 63, w = tid >> 6;

    // ---- phase 1: aggregate + stage own x ----
    {
        int g8 = lane >> 3, cj = lane & 7;
        int nl = w * 8 + g8;
        int node = node0 + nl;
        int beg = rowptr[node], end = rowptr[node + 1];
        float a[8] = {};
        int i = beg;
        for (; i + 1 < end; i += 2) {
            int u0 = col[i], u1 = col[i + 1];
            short8v v0 = *(const short8v*)(xb_in + (size_t)u0 * 64 + cj * 8);
            short8v v1 = *(const short8v*)(xb_in + (size_t)u1 * 64 + cj * 8);
#pragma unroll
            for (int j = 0; j < 8; ++j)
                a[j] += b2f((unsigned short)v0[j]) + b2f((unsigned short)v1[j]);
        }
        if (i < end) {
            int u = col[i];
            short8v v = *(const short8v*)(xb_in + (size_t)u * 64 + cj * 8);
#pragma unroll
            for (int j = 0; j < 8; ++j) a[j] += b2f((unsigned short)v[j]);
        }
        short8v r;
#pragma unroll
        for (int j = 0; j < 8; ++j) r[j] = (short)f2b(a[j]);
        *(short8v*)&s_lds[nl][cj * 8] = r;
        *(float4*)&x_lds[nl][cj * 8] = ((const float4*)(xb_in + (size_t)node * 64))[cj];
    }
    __syncthreads();

    // ---- phase 2: GRU MFMA ----
    int lr = lane & 15, lg = lane >> 4;
    short8v as_[2][2], ax_[2][2];
#pragma unroll
    for (int mt = 0; mt < 2; ++mt)
#pragma unroll
        for (int t = 0; t < 2; ++t) {
            int row = mt * 16 + lr, koff = t * 32 + lg * 8;
            as_[mt][t] = *(const short8v*)&s_lds[row][koff];
            ax_[mt][t] = *(const short8v*)&x_lds[row][koff];
        }

    f32x4 accA[3][2] = {};
    f32x4 accB[3][2] = {};
#pragma unroll
    for (int g = 0; g < 3; ++g) {
        int nt = g * 4 + w;
#pragma unroll
        for (int t = 0; t < 2; ++t) {
            const unsigned short* pA = Wgpk_l + ((size_t)((0 * 12 + nt) * 2 + t) * 64 + lane) * 8;
            const unsigned short* pB = Wgpk_l + ((size_t)((1 * 12 + nt) * 2 + t) * 64 + lane) * 8;
            short8v bA = *(const short8v*)pA;
            short8v bB = *(const short8v*)pB;
#pragma unroll
            for (int mt = 0; mt < 2; ++mt) {
                accA[g][mt] = __builtin_amdgcn_mfma_f32_16x16x32_bf16(as_[mt][t], bA, accA[g][mt], 0, 0, 0);
                accB[g][mt] = __builtin_amdgcn_mfma_f32_16x16x32_bf16(ax_[mt][t], bB, accB[g][mt], 0, 0, 0);
            }
        }
    }

    int ch = w * 16 + lr;
    float bi0 = bih[ch], bi1 = bih[64 + ch], bi2 = bih[128 + ch];
    float bh0 = bhh[ch], bh1 = bhh[64 + ch], bh2 = bhh[128 + ch];
    float xo[2][4];
#pragma unroll
    for (int mt = 0; mt < 2; ++mt) {
#pragma unroll
        for (int reg = 0; reg < 4; ++reg) {
            int m = mt * 16 + lg * 4 + reg;
            float r  = sigm(accA[0][mt][reg] + bi0 + accB[0][mt][reg] + bh0);
            float zg = sigm(accA[1][mt][reg] + bi1 + accB[1][mt][reg] + bh1);
            float nn = tanhf(accA[2][mt][reg] + bi2 + r * (accB[2][mt][reg] + bh2));
            xo[mt][reg] = (1.0f - zg) * nn + zg * xbuf[(size_t)(node0 + m) * 64 + ch];
        }
    }

    if (HAS_T == 0) {
        // last layer: write final x (fp32) for pooling
#pragma unroll
        for (int mt = 0; mt < 2; ++mt)
#pragma unroll
            for (int reg = 0; reg < 4; ++reg) {
                int m = mt * 16 + lg * 4 + reg;
                xbuf[(size_t)(node0 + m) * 64 + ch] = xo[mt][reg];
            }
        return;
    }

    // ---- phase 3: transform (next layer input) ----
#pragma unroll
    for (int mt = 0; mt < 2; ++mt)
#pragma unroll
        for (int reg = 0; reg < 4; ++reg) {
            int m = mt * 16 + lg * 4 + reg;
            a_lds[m][ch] = f2b(xo[mt][reg]);
        }
#pragma unroll
    for (int it = 0; it < 2; ++it) {
        int idx = it * 256 + tid;
        int n = idx >> 4, k4 = idx & 15;
        int z0 = z[(node0 + n) * 2], z1 = z[(node0 + n) * 2 + 1];
        float4 e0 = ((const float4*)(zemb_next + (size_t)z0 * 64))[k4];
        float4 e1 = ((const float4*)(zemb_next + (size_t)z1 * 64))[k4];
        ushort4 b;
        b.x = f2b(e0.x + e1.x); b.y = f2b(e0.y + e1.y);
        b.z = f2b(e0.z + e1.z); b.w = f2b(e0.w + e1.w);
        *(ushort4*)&a_lds[n][64 + k4 * 4] = b;
    }
    __syncthreads();

    f32x4 tacc[2] = {};
#pragma unroll
    for (int t = 0; t < 4; ++t) {
        const unsigned short* pB = tWpk_next + ((size_t)(w * 4 + t) * 64 + lane) * 8;
        short8v bf = *(const short8v*)pB;
#pragma unroll
        for (int mt = 0; mt < 2; ++mt) {
            int row = mt * 16 + lr, koff = t * 32 + lg * 8;
            short8v af = *(const short8v*)&a_lds[row][koff];
            tacc[mt] = __builtin_amdgcn_mfma_f32_16x16x32_bf16(af, bf, tacc[mt], 0, 0, 0);
        }
    }
    float tbc = tb_next[ch];
#pragma unroll
    for (int mt = 0; mt < 2; ++mt)
#pragma unroll
        for (int reg = 0; reg < 4; ++reg) {
            int m = mt * 16 + lg * 4 + reg;
            size_t o = (size_t)(node0 + m) * 64 + ch;
            float v = tacc[mt][reg] + tbc;
            xbuf[o] = v;
            xb_out[o] = f2b(v);
        }
}

// ---- segment-sum pooling via atomics ----
__global__ void pool_kernel(const float* __restrict__ in, const int* __restrict__ idx,
                            float* __restrict__ out, int rows) {
    int i = blockIdx.x * 256 + threadIdx.x;
    if (i >= rows * 64) return;
    int r = i >> 6, c = i & 63;
    atomicAdd(out + (size_t)idx[r] * 64 + c, in[i]);
}

// ---- in-place MLP: buf = relu(buf@W1+b1)@W2+b2, 4 rows per block ----
__global__ __launch_bounds__(256) void mlp_kernel(float* __restrict__ buf,
                                                  const float* __restrict__ W1,
                                                  const float* __restrict__ b1,
                                                  const float* __restrict__ W2,
                                                  const float* __restrict__ b2) {
    __shared__ float in_t[4][64];
    __shared__ float h_t[4][64];
    int tid = threadIdx.x;
    int c = tid & 63, r = tid >> 6;
    int row0 = blockIdx.x * 4;
    in_t[r][c] = buf[(size_t)(row0 + r) * 64 + c];
    __syncthreads();
    float acc = b1[c];
    for (int k = 0; k < 64; ++k) acc = fmaf(in_t[r][k], W1[k * 64 + c], acc);
    h_t[r][c] = fmaxf(acc, 0.0f);
    __syncthreads();
    acc = b2[c];
    for (int k = 0; k < 64; ++k) acc = fmaf(h_t[r][k], W2[k * 64 + c], acc);
    buf[(size_t)(row0 + r) * 64 + c] = acc;
}

// ---- final: g[64,64] -> fc1(elu) -> fc2(elu) -> fc3 -> out[64] ----
__global__ __launch_bounds__(256) void final_kernel(const float* __restrict__ g,
                                                    const float* __restrict__ fc1W, const float* __restrict__ fc1b,
                                                    const float* __restrict__ fc2W, const float* __restrict__ fc2b,
                                                    const float* __restrict__ fc3W, const float* __restrict__ fc3b,
                                                    float* __restrict__ out) {
    __shared__ float gt[64][64];
    __shared__ float h1[64][32];
    __shared__ float h2[64][16];
    int tid = threadIdx.x;
    for (int i = tid; i < 64 * 64; i += 256) gt[i >> 6][i & 63] = g[i];
    __syncthreads();
    for (int i = tid; i < 64 * 32; i += 256) {
        int r = i >> 5, c = i & 31;
        float acc = fc1b[c];
        for (int k = 0; k < 64; ++k) acc = fmaf(gt[r][k], fc1W[k * 32 + c], acc);
        h1[r][c] = elu(acc);
    }
    __syncthreads();
    for (int i = tid; i < 64 * 16; i += 256) {
        int r = i >> 4, c = i & 15;
        float acc = fc2b[c];
        for (int k = 0; k < 32; ++k) acc = fmaf(h1[r][k], fc2W[k * 16 + c], acc);
        h2[r][c] = elu(acc);
    }
    __syncthreads();
    if (tid < 64) {
        float acc = fc3b[0];
        for (int k = 0; k < 16; ++k) acc = fmaf(h2[tid][k], fc3W[k], acc);
        out[tid] = acc;
    }
}

extern "C" void kernel_launch(void* const* d_in, const int* in_sizes, int n_in,
                              void* d_out, int out_size, void* d_ws, size_t ws_size,
                              hipStream_t stream) {
    const int*   z     = (const int*)d_in[0];
    const int*   ei    = (const int*)d_in[1];
    const int*   n2s2  = (const int*)d_in[2];
    const int*   s22s  = (const int*)d_in[3];
    const int*   s2g   = (const int*)d_in[4];
    const float* z_emb = (const float*)d_in[5];
    const float* tW    = (const float*)d_in[6];
    const float* tb    = (const float*)d_in[7];
    const float* convW = (const float*)d_in[8];
    const float* gWih  = (const float*)d_in[9];
    const float* gbih  = (const float*)d_in[10];
    const float* gWhh  = (const float*)d_in[11];
    const float* gbhh  = (const float*)d_in[12];
    const float* epW1  = (const float*)d_in[13];
    const float* epb1  = (const float*)d_in[14];
    const float* epW2  = (const float*)d_in[15];
    const float* epb2  = (const float*)d_in[16];
    const float* npW1  = (const float*)d_in[17];
    const float* npb1  = (const float*)d_in[18];
    const float* npW2  = (const float*)d_in[19];
    const float* npb2  = (const float*)d_in[20];
    const float* fc1W  = (const float*)d_in[21];
    const float* fc1b  = (const float*)d_in[22];
    const float* fc2W  = (const float*)d_in[23];
    const float* fc2b  = (const float*)d_in[24];
    const float* fc3W  = (const float*)d_in[25];
    const float* fc3b  = (const float*)d_in[26];

    const int* srcp = ei;
    const int* dstp = ei + E;

    float*          xbuf = (float*)d_ws;                             // N*64 f32
    unsigned short* xbA  = (unsigned short*)(xbuf + (size_t)N * D);  // N*64 bf16
    unsigned short* xbB  = xbA + (size_t)N * D;                      // N*64 bf16
    float*          WihP = (float*)(xbB + (size_t)N * D);            // L*64*192
    int*            rowptr = (int*)(WihP + L * 64 * 192);            // N+1
    int*            colbuf = rowptr + (N + 1);                       // E
    int*            bbase  = colbuf + E;                             // NBUCK+1
    uintptr_t pal = (uintptr_t)(bbase + NBUCK + 1);
    pal = (pal + 15) & ~(uintptr_t)15;
    unsigned short* Wgpk = (unsigned short*)pal;                     // L*2*12*2*64*8 shorts
    unsigned short* tWpk = Wgpk + (size_t)L * 2 * 12 * 2 * 64 * 8;
    // CSR-build overlays on xbuf region (dead until embed): 12.8MB + 3.2MB < 25.6MB
    unsigned* tmp  = (unsigned*)xbuf;                                // NBUCK*NSTR*SCAP u32
    int*      bcnt = (int*)(tmp + (size_t)NBUCK * NSTR * SCAP);      // NBUCK*NSTR*16 ints
    // pooling overlays on colbuf (dead after last fused layer): 5.65MB < 6.4MB
    float* sg2  = (float*)colbuf;          // NSG2*64
    float* sg   = sg2 + (size_t)NSG2 * D;  // NSG*64
    float* gbuf = sg + (size_t)NSG * D;    // 64*64

    hipMemsetAsync(bcnt, 0, (size_t)NBUCK * NSTR * 16 * sizeof(int), stream);

    prep_kernel<<<(L * 64 * 192 + 255) / 256, 256, 0, stream>>>(convW, gWih, WihP);
    packg_kernel<<<(L * 2 * 12 * 2 * 64 + 255) / 256, 256, 0, stream>>>(WihP, gWhh, Wgpk);
    packt_kernel<<<((L - 1) * 4 * 4 * 64 + 255) / 256, 256, 0, stream>>>(tW, tWpk);

    bucketA_kernel<<<4096, 256, 0, stream>>>(srcp, dstp, bcnt, tmp);
    bscan_kernel<<<1, 1024, 0, stream>>>(bcnt, bbase, rowptr + N);
    bucketB_kernel<<<NBUCK, 256, 0, stream>>>(tmp, bcnt, bbase, rowptr, colbuf);

    embed_kernel<<<(N * 16 + 255) / 256, 256, 0, stream>>>(z, z_emb, xbuf, xbA);

    for (int l = 0; l < L; ++l) {
        const unsigned short* xin = (l & 1) ? xbB : xbA;
        unsigned short*       xout = (l & 1) ? xbA : xbB;
        if (l < L - 1) {
            fused_kernel<1><<<N / 32, 256, 0, stream>>>(
                xin, xbuf, xout, rowptr, colbuf,
                Wgpk + (size_t)l * 2 * 12 * 2 * 64 * 8,
                gbih + (size_t)l * 192, gbhh + (size_t)l * 192,
                z, z_emb + (size_t)(l + 1) * 100 * 64,
                tWpk + (size_t)l * 4 * 4 * 64 * 8, tb + (size_t)l * 64);
        } else {
            fused_kernel<0><<<N / 32, 256, 0, stream>>>(
                xin, xbuf, nullptr, rowptr, colbuf,
                Wgpk + (size_t)l * 2 * 12 * 2 * 64 * 8,
                gbih + (size_t)l * 192, gbhh + (size_t)l * 192,
                z, z_emb, tWpk, tb);
        }
    }

    // pooling chain: final x lives in xbuf (fp32)
    hipMemsetAsync(sg2, 0, (size_t)(NSG2 + NSG + NG) * D * sizeof(float), stream);
    pool_kernel<<<(N * D + 255) / 256, 256, 0, stream>>>(xbuf, n2s2, sg2, N);
    mlp_kernel<<<NSG2 / 4, 256, 0, stream>>>(sg2, epW1, epb1, epW2, epb2);
    pool_kernel<<<(NSG2 * D + 255) / 256, 256, 0, stream>>>(sg2, s22s, sg, NSG2);
    mlp_kernel<<<NSG / 4, 256, 0, stream>>>(sg, npW1, npb1, npW2, npb2);
    pool_kernel<<<(NSG * D + 255) / 256, 256, 0, stream>>>(sg, s2g, gbuf, NSG);
    final_kernel<<<1, 256, 0, stream>>>(gbuf, fc1W, fc1b, fc2W, fc2b, fc3W, fc3b, (float*)d_out);
}

// Round 8
// 498.878 us; speedup vs baseline: 3.9579x; 1.1127x over previous
//
#include <hip/hip_runtime.h>
#include <hip/hip_bf16.h>

constexpr int N    = 100000;
constexpr int E    = 1600000;
constexpr int NSG2 = 20000;
constexpr int NSG  = 2000;
constexpr int NG   = 64;
constexpr int D    = 64;
constexpr int L    = 5;

constexpr int NPB   = 32;                 // nodes per bucket
constexpr int NBUCK = N / NPB;            // 3125
constexpr int NSTR  = 8;                  // stripes (≈XCDs)
constexpr int SCAP  = 128;                // per (bucket,stripe) cap

typedef __attribute__((ext_vector_type(8))) short short8v;
typedef __attribute__((ext_vector_type(4))) float f32x4;

__device__ __forceinline__ float sigm(float x) { return 1.0f / (1.0f + expf(-x)); }
__device__ __forceinline__ float elu(float x)  { return x > 0.0f ? x : (expf(x) - 1.0f); }

__device__ __forceinline__ unsigned short f2b(float f) {
    union { float f; unsigned u; } x; x.f = f;
    unsigned r = (x.u + 0x7FFFu + ((x.u >> 16) & 1u)) >> 16;   // RNE
    return (unsigned short)r;
}
__device__ __forceinline__ float b2f(unsigned short h) {
    union { unsigned u; float f; } x; x.u = (unsigned)h << 16;
    return x.f;
}

// ---- WihP[l] = conv_W[l] @ gru_Wih[l]  (64x64 @ 64x192) ----
__global__ __launch_bounds__(256) void prep_kernel(const float* __restrict__ convW,
                                                   const float* __restrict__ Wih,
                                                   float* __restrict__ WihP) {
    int idx = blockIdx.x * 256 + threadIdx.x;   // L*64*192 = 61440
    if (idx >= L * 64 * 192) return;
    int l = idx / (64 * 192);
    int rem = idx % (64 * 192);
    int i = rem / 192, j = rem % 192;
    const float* W  = convW + l * 64 * 64;
    const float* Wi = Wih  + l * 64 * 192;
    float acc = 0.0f;
    for (int t = 0; t < 64; ++t) acc = fmaf(W[i * 64 + t], Wi[t * 192 + j], acc);
    WihP[idx] = acc;
}

// ---- pack GRU weights into bf16 MFMA B-fragments ----
__global__ __launch_bounds__(256) void packg_kernel(const float* __restrict__ WihP,
                                                    const float* __restrict__ gWhh,
                                                    unsigned short* __restrict__ Wgpk) {
    int idx = blockIdx.x * 256 + threadIdx.x;
    if (idx >= L * 2 * 12 * 2 * 64) return;
    int lane = idx & 63;
    int r1 = idx >> 6;
    int t  = r1 & 1;
    int r2 = r1 >> 1;
    int nt = r2 % 12;
    int lm = r2 / 12;             // l*2+mat
    int mat = lm & 1, l = lm >> 1;
    const float* W = mat ? (gWhh + (size_t)l * 64 * 192) : (WihP + (size_t)l * 64 * 192);
    int n  = nt * 16 + (lane & 15);
    int k0 = t * 32 + (lane >> 4) * 8;
    short8v v;
#pragma unroll
    for (int j = 0; j < 8; ++j) v[j] = (short)f2b(W[(k0 + j) * 192 + n]);
    *(short8v*)(Wgpk + (size_t)idx * 8) = v;
}

// ---- pack transform weights ----
__global__ __launch_bounds__(256) void packt_kernel(const float* __restrict__ tW,
                                                    unsigned short* __restrict__ tWpk) {
    int idx = blockIdx.x * 256 + threadIdx.x;
    if (idx >= (L - 1) * 4 * 4 * 64) return;
    int lane = idx & 63;
    int r1 = idx >> 6;
    int t  = r1 & 3;
    int r2 = r1 >> 2;
    int nt = r2 & 3;
    int lm = r2 >> 2;
    const float* W = tW + (size_t)lm * 128 * 64;
    int n  = nt * 16 + (lane & 15);
    int k0 = t * 32 + (lane >> 4) * 8;
    short8v v;
#pragma unroll
    for (int j = 0; j < 8; ++j) v[j] = (short)f2b(W[(k0 + j) * 64 + n]);
    *(short8v*)(tWpk + (size_t)idx * 8) = v;
}

// ---- CSR build: striped bucket append; stripe-major layout (stripe ≈ XCD) ----
__global__ void bucketA_kernel(const int* __restrict__ src, const int* __restrict__ dst,
                               int* __restrict__ bcnt, unsigned* __restrict__ tmp) {
    int stripe = blockIdx.x & (NSTR - 1);
    for (int e = blockIdx.x * blockDim.x + threadIdx.x; e < E; e += gridDim.x * blockDim.x) {
        int d = dst[e];
        int cell = stripe * NBUCK + (d >> 5);
        int pos = atomicAdd(&bcnt[cell * 16], 1);   // 64B-strided counters
        if (pos < SCAP)
            tmp[(size_t)cell * SCAP + pos] = ((unsigned)(d & 31) << 17) | (unsigned)src[e];
    }
}

__global__ __launch_bounds__(1024) void bscan_kernel(const int* __restrict__ bcnt,
                                                     int* __restrict__ bbase,
                                                     int* __restrict__ rowptrN) {
    __shared__ int part[1024];
    int t = threadIdx.x;
    int loc[4]; int sum = 0;
#pragma unroll
    for (int j = 0; j < 4; ++j) {
        int b = t * 4 + j; int v = 0;
        if (b < NBUCK) {
#pragma unroll
            for (int s = 0; s < NSTR; ++s) v += min(bcnt[(s * NBUCK + b) * 16], SCAP);
        }
        loc[j] = v; sum += v;
    }
    part[t] = sum;
    __syncthreads();
    for (int off = 1; off < 1024; off <<= 1) {
        int u = (t >= off) ? part[t - off] : 0;
        __syncthreads();
        part[t] += u;
        __syncthreads();
    }
    int run = part[t] - sum;
#pragma unroll
    for (int j = 0; j < 4; ++j) {
        int b = t * 4 + j;
        if (b < NBUCK) bbase[b] = run;
        run += loc[j];
    }
    if (t == 1023) { bbase[NBUCK] = part[1023]; rowptrN[0] = part[1023]; }
}

// ---- fused per-bucket: stripes -> LDS, histogram, scan -> rowptr, scatter -> col ----
__global__ __launch_bounds__(256) void bucketB_kernel(const unsigned* __restrict__ tmp,
                                                      const int* __restrict__ bcnt,
                                                      const int* __restrict__ bbase,
                                                      int* __restrict__ rowptr,
                                                      int* __restrict__ col) {
    __shared__ unsigned recs[NSTR * SCAP];
    __shared__ int scnt[NSTR];
    __shared__ int soff[NSTR + 1];
    __shared__ int cur[NPB];
    int b = blockIdx.x, tid = threadIdx.x;
    if (tid < NSTR) scnt[tid] = min(bcnt[(tid * NBUCK + b) * 16], SCAP);
    if (tid < NPB) cur[tid] = 0;
    __syncthreads();
    if (tid == 0) {
        int r = 0;
        for (int s = 0; s < NSTR; ++s) { soff[s] = r; r += scnt[s]; }
        soff[NSTR] = r;
    }
    __syncthreads();
    int total = soff[NSTR];
    for (int i = tid; i < NSTR * SCAP; i += 256) {
        int s = i >> 7, k = i & (SCAP - 1);
        if (k < scnt[s]) recs[soff[s] + k] = tmp[((size_t)s * NBUCK + b) * SCAP + k];
    }
    __syncthreads();
    for (int i = tid; i < total; i += 256) atomicAdd(&cur[recs[i] >> 17], 1);
    __syncthreads();
    if (tid == 0) {
        int base = bbase[b], r = 0;
        for (int j = 0; j < NPB; ++j) {
            int v = cur[j];
            cur[j] = base + r;
            rowptr[b * NPB + j] = base + r;
            r += v;
        }
    }
    __syncthreads();
    for (int i = tid; i < total; i += 256) {
        unsigned w = recs[i];
        int pos = atomicAdd(&cur[w >> 17], 1);
        col[pos] = (int)(w & 0x1FFFFu);
    }
}

// ---- x0 = z_emb[0][z].sum(1) -> fp32 + bf16 mirror (float4) ----
__global__ __launch_bounds__(256) void embed_kernel(const int* __restrict__ z,
                                                    const float* __restrict__ zemb0,
                                                    float* __restrict__ x,
                                                    unsigned short* __restrict__ xb) {
    int idx = blockIdx.x * 256 + threadIdx.x;  // N*16 float4 units
    if (idx >= N * 16) return;
    int n = idx >> 4, k4 = idx & 15;
    float4 e0 = ((const float4*)(zemb0 + (size_t)z[n * 2] * 64))[k4];
    float4 e1 = ((const float4*)(zemb0 + (size_t)z[n * 2 + 1] * 64))[k4];
    float4 v; v.x = e0.x + e1.x; v.y = e0.y + e1.y; v.z = e0.z + e1.z; v.w = e0.w + e1.w;
    ((float4*)x)[idx] = v;
    ushort4 b; b.x = f2b(v.x); b.y = f2b(v.y); b.z = f2b(v.z); b.w = f2b(v.w);
    ((ushort4*)xb)[idx] = b;
}

// ---- fused layer: aggregate (deep-pipelined gather) -> GRU MFMA -> [transform MFMA] ----
template<int HAS_T>
__global__ __launch_bounds__(256) void fused_kernel(const unsigned short* __restrict__ xb_in,
                                                    float* __restrict__ xbuf,
                                                    unsigned short* __restrict__ xb_out,
                                                    const int* __restrict__ rowptr,
                                                    const int* __restrict__ col,
                                                    const unsigned short* __restrict__ Wgpk_l,
                                                    const float* __restrict__ bih,
                                                    const float* __restrict__ bhh,
                                                    const int* __restrict__ z,
                                                    const float* __restrict__ zemb_next,
                                                    const unsigned short* __restrict__ tWpk_next,
                                                    const float* __restrict__ tb_next) {
    __shared__ union {
        struct { unsigned short s[32][72]; unsigned short x[32][72]; } p1;  // 9216 B
        unsigned short a[32][136];                                          // 8704 B
    } u;
    int tid = threadIdx.x;
    int node0 = blockIdx.x * 32;
    int lane = tid & 63, w = tid >> 6;

    // ---- phase 1: aggregate, 8/4/2/1-deep pipelined gather ----
    {
        int g8 = lane >> 3, cj = lane & 7;
        int nl = w * 8 + g8;
        int node = node0 + nl;
        // own-x load issued first, consumed at the end
        float4 ownx = ((const float4*)(xb_in + (size_t)node * 64))[cj];
        int beg = rowptr[node], end = rowptr[node + 1];
        float a[8] = {};
        const unsigned short* __restrict__ xbc = xb_in + cj * 8;
        int i = beg;
        for (; i + 8 <= end; i += 8) {
            int u0 = col[i],     u1 = col[i + 1], u2 = col[i + 2], u3 = col[i + 3];
            int u4 = col[i + 4], u5 = col[i + 5], u6 = col[i + 6], u7 = col[i + 7];
            short8v v0 = *(const short8v*)(xbc + (size_t)u0 * 64);
            short8v v1 = *(const short8v*)(xbc + (size_t)u1 * 64);
            short8v v2 = *(const short8v*)(xbc + (size_t)u2 * 64);
            short8v v3 = *(const short8v*)(xbc + (size_t)u3 * 64);
            short8v v4 = *(const short8v*)(xbc + (size_t)u4 * 64);
            short8v v5 = *(const short8v*)(xbc + (size_t)u5 * 64);
            short8v v6 = *(const short8v*)(xbc + (size_t)u6 * 64);
            short8v v7 = *(const short8v*)(xbc + (size_t)u7 * 64);
#pragma unroll
            for (int j = 0; j < 8; ++j)
                a[j] += ((b2f((unsigned short)v0[j]) + b2f((unsigned short)v1[j])) +
                         (b2f((unsigned short)v2[j]) + b2f((unsigned short)v3[j]))) +
                        ((b2f((unsigned short)v4[j]) + b2f((unsigned short)v5[j])) +
                         (b2f((unsigned short)v6[j]) + b2f((unsigned short)v7[j])));
        }
        for (; i + 4 <= end; i += 4) {
            int u0 = col[i], u1 = col[i + 1], u2 = col[i + 2], u3 = col[i + 3];
            short8v v0 = *(const short8v*)(xbc + (size_t)u0 * 64);
            short8v v1 = *(const short8v*)(xbc + (size_t)u1 * 64);
            short8v v2 = *(const short8v*)(xbc + (size_t)u2 * 64);
            short8v v3 = *(const short8v*)(xbc + (size_t)u3 * 64);
#pragma unroll
            for (int j = 0; j < 8; ++j)
                a[j] += (b2f((unsigned short)v0[j]) + b2f((unsigned short)v1[j])) +
                        (b2f((unsigned short)v2[j]) + b2f((unsigned short)v3[j]));
        }
        for (; i + 2 <= end; i += 2) {
            int u0 = col[i], u1 = col[i + 1];
            short8v v0 = *(const short8v*)(xbc + (size_t)u0 * 64);
            short8v v1 = *(const short8v*)(xbc + (size_t)u1 * 64);
#pragma unroll
            for (int j = 0; j < 8; ++j)
                a[j] += b2f((unsigned short)v0[j]) + b2f((unsigned short)v1[j]);
        }
        if (i < end) {
            short8v v = *(const short8v*)(xbc + (size_t)col[i] * 64);
#pragma unroll
            for (int j = 0; j < 8; ++j) a[j] += b2f((unsigned short)v[j]);
        }
        short8v r;
#pragma unroll
        for (int j = 0; j < 8; ++j) r[j] = (short)f2b(a[j]);
        *(short8v*)&u.p1.s[nl][cj * 8] = r;
        *(float4*)&u.p1.x[nl][cj * 8] = ownx;
    }
    __syncthreads();

    // ---- phase 2: GRU MFMA ----
    int lr = lane & 15, lg = lane >> 4;
    short8v as_[2][2], ax_[2][2];
#pragma unroll
    for (int mt = 0; mt < 2; ++mt)
#pragma unroll
        for (int t = 0; t < 2; ++t) {
            int row = mt * 16 + lr, koff = t * 32 + lg * 8;
            as_[mt][t] = *(const short8v*)&u.p1.s[row][koff];
            ax_[mt][t] = *(const short8v*)&u.p1.x[row][koff];
        }
    if (HAS_T) __syncthreads();   // all frag reads done before a-tile aliasing writes

    f32x4 accA[3][2] = {};
    f32x4 accB[3][2] = {};
#pragma unroll
    for (int g = 0; g < 3; ++g) {
        int nt = g * 4 + w;
#pragma unroll
        for (int t = 0; t < 2; ++t) {
            const unsigned short* pA = Wgpk_l + ((size_t)((0 * 12 + nt) * 2 + t) * 64 + lane) * 8;
            const unsigned short* pB = Wgpk_l + ((size_t)((1 * 12 + nt) * 2 + t) * 64 + lane) * 8;
            short8v bA = *(const short8v*)pA;
            short8v bB = *(const short8v*)pB;
#pragma unroll
            for (int mt = 0; mt < 2; ++mt) {
                accA[g][mt] = __builtin_amdgcn_mfma_f32_16x16x32_bf16(as_[mt][t], bA, accA[g][mt], 0, 0, 0);
                accB[g][mt] = __builtin_amdgcn_mfma_f32_16x16x32_bf16(ax_[mt][t], bB, accB[g][mt], 0, 0, 0);
            }
        }
    }

    int ch = w * 16 + lr;
    float bi0 = bih[ch], bi1 = bih[64 + ch], bi2 = bih[128 + ch];
    float bh0 = bhh[ch], bh1 = bhh[64 + ch], bh2 = bhh[128 + ch];
    float xo[2][4];
#pragma unroll
    for (int mt = 0; mt < 2; ++mt) {
#pragma unroll
        for (int reg = 0; reg < 4; ++reg) {
            int m = mt * 16 + lg * 4 + reg;
            float r  = sigm(accA[0][mt][reg] + bi0 + accB[0][mt][reg] + bh0);
            float zg = sigm(accA[1][mt][reg] + bi1 + accB[1][mt][reg] + bh1);
            float nn = tanhf(accA[2][mt][reg] + bi2 + r * (accB[2][mt][reg] + bh2));
            xo[mt][reg] = (1.0f - zg) * nn + zg * xbuf[(size_t)(node0 + m) * 64 + ch];
        }
    }

    if (HAS_T == 0) {
#pragma unroll
        for (int mt = 0; mt < 2; ++mt)
#pragma unroll
            for (int reg = 0; reg < 4; ++reg) {
                int m = mt * 16 + lg * 4 + reg;
                xbuf[(size_t)(node0 + m) * 64 + ch] = xo[mt][reg];
            }
        return;
    }

    // ---- phase 3: transform (next layer input) ----
#pragma unroll
    for (int mt = 0; mt < 2; ++mt)
#pragma unroll
        for (int reg = 0; reg < 4; ++reg) {
            int m = mt * 16 + lg * 4 + reg;
            u.a[m][ch] = f2b(xo[mt][reg]);
        }
#pragma unroll
    for (int it = 0; it < 2; ++it) {
        int idx = it * 256 + tid;
        int n = idx >> 4, k4 = idx & 15;
        int z0 = z[(node0 + n) * 2], z1 = z[(node0 + n) * 2 + 1];
        float4 e0 = ((const float4*)(zemb_next + (size_t)z0 * 64))[k4];
        float4 e1 = ((const float4*)(zemb_next + (size_t)z1 * 64))[k4];
        ushort4 b;
        b.x = f2b(e0.x + e1.x); b.y = f2b(e0.y + e1.y);
        b.z = f2b(e0.z + e1.z); b.w = f2b(e0.w + e1.w);
        *(ushort4*)&u.a[n][64 + k4 * 4] = b;
    }
    __syncthreads();

    f32x4 tacc[2] = {};
#pragma unroll
    for (int t = 0; t < 4; ++t) {
        const unsigned short* pB = tWpk_next + ((size_t)(w * 4 + t) * 64 + lane) * 8;
        short8v bf = *(const short8v*)pB;
#pragma unroll
        for (int mt = 0; mt < 2; ++mt) {
            int row = mt * 16 + lr, koff = t * 32 + lg * 8;
            short8v af = *(const short8v*)&u.a[row][koff];
            tacc[mt] = __builtin_amdgcn_mfma_f32_16x16x32_bf16(af, bf, tacc[mt], 0, 0, 0);
        }
    }
    float tbc = tb_next[ch];
#pragma unroll
    for (int mt = 0; mt < 2; ++mt)
#pragma unroll
        for (int reg = 0; reg < 4; ++reg) {
            int m = mt * 16 + lg * 4 + reg;
            size_t o = (size_t)(node0 + m) * 64 + ch;
            float v = tacc[mt][reg] + tbc;
            xbuf[o] = v;
            xb_out[o] = f2b(v);
        }
}

// ---- segment-sum pooling via atomics ----
__global__ void pool_kernel(const float* __restrict__ in, const int* __restrict__ idx,
                            float* __restrict__ out, int rows) {
    int i = blockIdx.x * 256 + threadIdx.x;
    if (i >= rows * 64) return;
    int r = i >> 6, c = i & 63;
    atomicAdd(out + (size_t)idx[r] * 64 + c, in[i]);
}

// ---- in-place MLP: buf = relu(buf@W1+b1)@W2+b2, 4 rows per block ----
__global__ __launch_bounds__(256) void mlp_kernel(float* __restrict__ buf,
                                                  const float* __restrict__ W1,
                                                  const float* __restrict__ b1,
                                                  const float* __restrict__ W2,
                                                  const float* __restrict__ b2) {
    __shared__ float in_t[4][64];
    __shared__ float h_t[4][64];
    int tid = threadIdx.x;
    int c = tid & 63, r = tid >> 6;
    int row0 = blockIdx.x * 4;
    in_t[r][c] = buf[(size_t)(row0 + r) * 64 + c];
    __syncthreads();
    float acc = b1[c];
    for (int k = 0; k < 64; ++k) acc = fmaf(in_t[r][k], W1[k * 64 + c], acc);
    h_t[r][c] = fmaxf(acc, 0.0f);
    __syncthreads();
    acc = b2[c];
    for (int k = 0; k < 64; ++k) acc = fmaf(h_t[r][k], W2[k * 64 + c], acc);
    buf[(size_t)(row0 + r) * 64 + c] = acc;
}

// ---- final: g[64,64] -> fc1(elu) -> fc2(elu) -> fc3 -> out[64] ----
__global__ __launch_bounds__(256) void final_kernel(const float* __restrict__ g,
                                                    const float* __restrict__ fc1W, const float* __restrict__ fc1b,
                                                    const float* __restrict__ fc2W, const float* __restrict__ fc2b,
                                                    const float* __restrict__ fc3W, const float* __restrict__ fc3b,
                                                    float* __restrict__ out) {
    __shared__ float gt[64][64];
    __shared__ float h1[64][32];
    __shared__ float h2[64][16];
    int tid = threadIdx.x;
    for (int i = tid; i < 64 * 64; i += 256) gt[i >> 6][i & 63] = g[i];
    __syncthreads();
    for (int i = tid; i < 64 * 32; i += 256) {
        int r = i >> 5, c = i & 31;
        float acc = fc1b[c];
        for (int k = 0; k < 64; ++k) acc = fmaf(gt[r][k], fc1W[k * 32 + c], acc);
        h1[r][c] = elu(acc);
    }
    __syncthreads();
    for (int i = tid; i < 64 * 16; i += 256) {
        int r = i >> 4, c = i & 15;
        float acc = fc2b[c];
        for (int k = 0; k < 32; ++k) acc = fmaf(h1[r][k], fc2W[k * 16 + c], acc);
        h2[r][c] = elu(acc);
    }
    __syncthreads();
    if (tid < 64) {
        float acc = fc3b[0];
        for (int k = 0; k < 16; ++k) acc = fmaf(h2[tid][k], fc3W[k], acc);
        out[tid] = acc;
    }
}

extern "C" void kernel_launch(void* const* d_in, const int* in_sizes, int n_in,
                              void* d_out, int out_size, void* d_ws, size_t ws_size,
                              hipStream_t stream) {
    const int*   z     = (const int*)d_in[0];
    const int*   ei    = (const int*)d_in[1];
    const int*   n2s2  = (const int*)d_in[2];
    const int*   s22s  = (const int*)d_in[3];
    const int*   s2g   = (const int*)d_in[4];
    const float* z_emb = (const float*)d_in[5];
    const float* tW    = (const float*)d_in[6];
    const float* tb    = (const float*)d_in[7];
    const float* convW = (const float*)d_in[8];
    const float* gWih  = (const float*)d_in[9];
    const float* gbih  = (const float*)d_in[10];
    const float* gWhh  = (const float*)d_in[11];
    const float* gbhh  = (const float*)d_in[12];
    const float* epW1  = (const float*)d_in[13];
    const float* epb1  = (const float*)d_in[14];
    const float* epW2  = (const float*)d_in[15];
    const float* epb2  = (const float*)d_in[16];
    const float* npW1  = (const float*)d_in[17];
    const float* npb1  = (const float*)d_in[18];
    const float* npW2  = (const float*)d_in[19];
    const float* npb2  = (const float*)d_in[20];
    const float* fc1W  = (const float*)d_in[21];
    const float* fc1b  = (const float*)d_in[22];
    const float* fc2W  = (const float*)d_in[23];
    const float* fc2b  = (const float*)d_in[24];
    const float* fc3W  = (const float*)d_in[25];
    const float* fc3b  = (const float*)d_in[26];

    const int* srcp = ei;
    const int* dstp = ei + E;

    float*          xbuf = (float*)d_ws;                             // N*64 f32
    unsigned short* xbA  = (unsigned short*)(xbuf + (size_t)N * D);  // N*64 bf16
    unsigned short* xbB  = xbA + (size_t)N * D;                      // N*64 bf16
    float*          WihP = (float*)(xbB + (size_t)N * D);            // L*64*192
    int*            rowptr = (int*)(WihP + L * 64 * 192);            // N+1
    int*            colbuf = rowptr + (N + 1);                       // E
    int*            bbase  = colbuf + E;                             // NBUCK+1
    uintptr_t pal = (uintptr_t)(bbase + NBUCK + 1);
    pal = (pal + 15) & ~(uintptr_t)15;
    unsigned short* Wgpk = (unsigned short*)pal;                     // L*2*12*2*64*8 shorts
    unsigned short* tWpk = Wgpk + (size_t)L * 2 * 12 * 2 * 64 * 8;
    // CSR-build overlays on xbuf region (dead until embed)
    unsigned* tmp  = (unsigned*)xbuf;                                // NSTR*NBUCK*SCAP u32
    int*      bcnt = (int*)(tmp + (size_t)NSTR * NBUCK * SCAP);      // NSTR*NBUCK*16 ints
    // pooling overlays on colbuf (dead after last fused layer)
    float* sg2  = (float*)colbuf;          // NSG2*64
    float* sg   = sg2 + (size_t)NSG2 * D;  // NSG*64
    float* gbuf = sg + (size_t)NSG * D;    // 64*64

    hipMemsetAsync(bcnt, 0, (size_t)NSTR * NBUCK * 16 * sizeof(int), stream);

    prep_kernel<<<(L * 64 * 192 + 255) / 256, 256, 0, stream>>>(convW, gWih, WihP);
    packg_kernel<<<(L * 2 * 12 * 2 * 64 + 255) / 256, 256, 0, stream>>>(WihP, gWhh, Wgpk);
    packt_kernel<<<((L - 1) * 4 * 4 * 64 + 255) / 256, 256, 0, stream>>>(tW, tWpk);

    bucketA_kernel<<<4096, 256, 0, stream>>>(srcp, dstp, bcnt, tmp);
    bscan_kernel<<<1, 1024, 0, stream>>>(bcnt, bbase, rowptr + N);
    bucketB_kernel<<<NBUCK, 256, 0, stream>>>(tmp, bcnt, bbase, rowptr, colbuf);

    embed_kernel<<<(N * 16 + 255) / 256, 256, 0, stream>>>(z, z_emb, xbuf, xbA);

    for (int l = 0; l < L; ++l) {
        const unsigned short* xin = (l & 1) ? xbB : xbA;
        unsigned short*       xout = (l & 1) ? xbA : xbB;
        if (l < L - 1) {
            fused_kernel<1><<<N / 32, 256, 0, stream>>>(
                xin, xbuf, xout, rowptr, colbuf,
                Wgpk + (size_t)l * 2 * 12 * 2 * 64 * 8,
                gbih + (size_t)l * 192, gbhh + (size_t)l * 192,
                z, z_emb + (size_t)(l + 1) * 100 * 64,
                tWpk + (size_t)l * 4 * 4 * 64 * 8, tb + (size_t)l * 64);
        } else {
            fused_kernel<0><<<N / 32, 256, 0, stream>>>(
                xin, xbuf, nullptr, rowptr, colbuf,
                Wgpk + (size_t)l * 2 * 12 * 2 * 64 * 8,
                gbih + (size_t)l * 192, gbhh + (size_t)l * 192,
                z, z_emb, tWpk, tb);
        }
    }

    // pooling chain: final x lives in xbuf (fp32)
    hipMemsetAsync(sg2, 0, (size_t)(NSG2 + NSG + NG) * D * sizeof(float), stream);
    pool_kernel<<<(N * D + 255) / 256, 256, 0, stream>>>(xbuf, n2s2, sg2, N);
    mlp_kernel<<<NSG2 / 4, 256, 0, stream>>>(sg2, epW1, epb1, epW2, epb2);
    pool_kernel<<<(NSG2 * D + 255) / 256, 256, 0, stream>>>(sg2, s22s, sg, NSG2);
    mlp_kernel<<<NSG / 4, 256, 0, stream>>>(sg, npW1, npb1, npW2, npb2);
    pool_kernel<<<(NSG * D + 255) / 256, 256, 0, stream>>>(sg, s2g, gbuf, NSG);
    final_kernel<<<1, 256, 0, stream>>>(gbuf, fc1W, fc1b, fc2W, fc2b, fc3W, fc3b, (float*)d_out);
}